// Round 19
// baseline (383.416 us; speedup 1.0000x reference)
//
#include <hip/hip_runtime.h>

#define NN 20000
#define EE 320000
#define ET (EE + NN)

typedef __attribute__((ext_vector_type(8))) short short8v;
typedef __attribute__((ext_vector_type(4))) float float4v;

__device__ __forceinline__ float b2f(unsigned short u) {
  union { float f; unsigned int i; } c; c.i = ((unsigned int)u) << 16; return c.f;
}
__device__ __forceinline__ unsigned short f2bs(float f) {  // f32 -> bf16 bits, RNE
  union { float f; unsigned int u; } c; c.f = f;
  unsigned int r = c.u + 0x7fffu + ((c.u >> 16) & 1u);
  return (unsigned short)(r >> 16);
}

// ---------------- input dtype detector (flag=1 -> f32, flag=0 -> bf16) ----------------
__global__ void detect_kernel(const unsigned short* __restrict__ x, int* __restrict__ flag) {
  __shared__ int cnt_s;
  if (threadIdx.x == 0) cnt_s = 0;
  __syncthreads();
  int pass = 0;
  for (int j = 0; j < 16; ++j) {
    unsigned short u = x[2 * (threadIdx.x * 16 + j)];
    int e = (u >> 7) & 0xFF;
    if (e >= 96 && e <= 150) pass++;
  }
  atomicAdd(&cnt_s, pass);
  __syncthreads();
  if (threadIdx.x == 0) *flag = (cnt_s < 2458) ? 1 : 0;
}

// x -> hi/lo bf16 (residual recovered as hi+lo; no f32 copy)
__global__ void convert_x_kernel(const void* __restrict__ in,
                                 short* __restrict__ xh, short* __restrict__ xl, int n4,
                                 const int* __restrict__ flag) {
  int i = blockIdx.x * 256 + threadIdx.x;
  if (i >= n4) return;
  float4 v;
  if (*flag) {
    v = ((const float4*)in)[i];
  } else {
    ushort4 u = ((const ushort4*)in)[i];
    v = make_float4(b2f(u.x), b2f(u.y), b2f(u.z), b2f(u.w));
  }
  ushort4 h, l;
  h.x = f2bs(v.x); l.x = f2bs(v.x - b2f(h.x));
  h.y = f2bs(v.y); l.y = f2bs(v.y - b2f(h.y));
  h.z = f2bs(v.z); l.z = f2bs(v.z - b2f(h.z));
  h.w = f2bs(v.w); l.w = f2bs(v.w - b2f(h.w));
  ((ushort4*)xh)[i] = h;
  ((ushort4*)xl)[i] = l;
}

struct WSpec { const void* p[28]; int off[28]; int len[28]; };
__global__ void convert_weights(WSpec ws, float* __restrict__ out, const int* __restrict__ flag) {
  int b = blockIdx.x;
  int f32m = *flag;
  const void* p = ws.p[b];
  int off = ws.off[b], len4 = ws.len[b] >> 2;
  float4* dst = (float4*)(out + off);
  for (int i = blockIdx.y * 256 + threadIdx.x; i < len4; i += 8 * 256) {
    if (f32m) {
      dst[i] = ((const float4*)p)[i];
    } else {
      ushort4 u = ((const ushort4*)p)[i];
      dst[i] = make_float4(b2f(u.x), b2f(u.y), b2f(u.z), b2f(u.w));
    }
  }
}

// W [K x N] row-major (ldb=N) -> k-chunked hi/lo bf16: element (n,k) at ((k>>3)*N+n)*8+(k&7)
__global__ void bconv_kernel(const float* __restrict__ W, int ldb,
                             short* __restrict__ Bh, short* __restrict__ Bl, int N) {
  int idx = blockIdx.x * 256 + threadIdx.x;
  if (idx >= N * 256) return;
  int n = idx >> 8, k = idx & 255;
  float v = W[(size_t)k * ldb + n];
  unsigned short h = f2bs(v);
  size_t o = ((size_t)(k >> 3) * N + n) * 8 + (k & 7);
  Bh[o] = (short)h;
  Bl[o] = (short)f2bs(v - b2f(h));
}

// ---------------- graph prep: degrees + CSR ----------------
__global__ void count_kernel(const int* __restrict__ ei, int* __restrict__ cnt) {
  int e = blockIdx.x * 256 + threadIdx.x;
  if (e >= ET) return;
  int dst = (e < EE) ? ei[EE + e] : (e - EE);
  atomicAdd(&cnt[dst], 1);
}

__global__ void dis_kernel(const int* __restrict__ cnt, float* __restrict__ dis) {
  int i = blockIdx.x * 256 + threadIdx.x;
  if (i >= NN) return;
  dis[i] = rsqrtf((float)cnt[i] + 1e-6f);
}

// 2-level scan
__global__ void scan1_kernel(const int* __restrict__ cnt, int* __restrict__ partial,
                             int* __restrict__ bsum) {
  __shared__ int sd[256];
  int b = blockIdx.x, t = threadIdx.x;
  int i = b * 256 + t;
  sd[t] = (i < NN) ? cnt[i] : 0;
  __syncthreads();
  for (int off = 1; off < 256; off <<= 1) {
    int x = (t >= off) ? sd[t - off] : 0;
    __syncthreads();
    sd[t] += x;
    __syncthreads();
  }
  if (i < NN) partial[i] = sd[t];
  if (t == 255) bsum[b] = sd[255];
}

__global__ void scan2_kernel(int* __restrict__ bsum, int nb) {
  __shared__ int sd[128];
  int t = threadIdx.x;
  sd[t] = (t < nb) ? bsum[t] : 0;
  __syncthreads();
  for (int off = 1; off < 128; off <<= 1) {
    int x = (t >= off) ? sd[t - off] : 0;
    __syncthreads();
    sd[t] += x;
    __syncthreads();
  }
  if (t < nb) bsum[t] = sd[t];
}

__global__ void scan3_kernel(const int* __restrict__ partial, const int* __restrict__ bsum,
                             int* __restrict__ rowptr) {
  int i = blockIdx.x * 256 + threadIdx.x;
  if (i == 0) rowptr[0] = 0;
  if (i < NN) {
    int b = i >> 8;
    rowptr[i + 1] = partial[i] + (b ? bsum[b - 1] : 0);
  }
}

// packed CSR entry: .x = src, .y = coef bits; edge_attr read raw with dtype flag
__global__ void fill_kernel(const int* __restrict__ ei, const void* __restrict__ ea,
                            const float* __restrict__ dis, const int* __restrict__ rowptr,
                            int* __restrict__ cursor, int2* __restrict__ csr,
                            float* __restrict__ sarr, const int* __restrict__ flag) {
  int e = blockIdx.x * 256 + threadIdx.x;
  if (e >= ET) return;
  int src, dst; float a;
  if (e < EE) {
    src = ei[e]; dst = ei[EE + e];
    a = (*flag) ? ((const float*)ea)[e] : b2f(((const unsigned short*)ea)[e]);
  } else {
    src = dst = e - EE; a = 0.f;
  }
  float coef = dis[src] * dis[dst];
  int pos = rowptr[dst] + atomicAdd(&cursor[dst], 1);
  csr[pos] = make_int2(src, __float_as_int(coef));
  if (a != 0.f) atomicAdd(&sarr[dst], coef * a);
}

// ---------------- batched small GEMMs (64x64 tile, 4x4 micro) ----------------
struct GJobs {
  const float* A[8]; const float* B[8]; float* C[8];
  int M[8], N[8], K[8], ldc[8], blkx[8], cum[8];
  int njobs;
};
__global__ __launch_bounds__(256) void gemm64_multi(GJobs jb) {
  int bid = blockIdx.x;
  int j = 0;
  while (j < jb.njobs - 1 && bid >= jb.cum[j]) ++j;
  int local = bid - (j ? jb.cum[j - 1] : 0);
  const float* A = jb.A[j];
  const float* B = jb.B[j];
  float* C = jb.C[j];
  int M = jb.M[j], N = jb.N[j], K = jb.K[j], ldc = jb.ldc[j];
  int bx = local % jb.blkx[j], by = local / jb.blkx[j];

  __shared__ float As[16][68];
  __shared__ float Bs[16][64];
  int tid = threadIdx.x;
  int row0 = bx * 64, col0 = by * 64;
  int tr = tid >> 4, tc = tid & 15;
  float acc[4][4] = {};
  int lmA = tid >> 2;
  int lkA = (tid & 3) << 2;
  int lkB = tid >> 4;
  int lcB = (tid & 15) << 2;
  for (int k0 = 0; k0 < K; k0 += 16) {
    int gr = row0 + lmA;
    float4 a4 = make_float4(0.f, 0.f, 0.f, 0.f);
    if (gr < M) a4 = *reinterpret_cast<const float4*>(&A[(size_t)gr * K + k0 + lkA]);
    As[lkA + 0][lmA] = a4.x;
    As[lkA + 1][lmA] = a4.y;
    As[lkA + 2][lmA] = a4.z;
    As[lkA + 3][lmA] = a4.w;
    float4 b4 = *reinterpret_cast<const float4*>(&B[(size_t)(k0 + lkB) * N + col0 + lcB]);
    *reinterpret_cast<float4*>(&Bs[lkB][lcB]) = b4;
    __syncthreads();
#pragma unroll
    for (int kk = 0; kk < 16; ++kk) {
      float4 av = *reinterpret_cast<const float4*>(&As[kk][tr << 2]);
      float4 bv = *reinterpret_cast<const float4*>(&Bs[kk][tc << 2]);
      float aa[4] = {av.x, av.y, av.z, av.w};
      float bb[4] = {bv.x, bv.y, bv.z, bv.w};
#pragma unroll
      for (int i = 0; i < 4; ++i)
#pragma unroll
        for (int jj = 0; jj < 4; ++jj) acc[i][jj] += aa[i] * bb[jj];
    }
    __syncthreads();
  }
#pragma unroll
  for (int i = 0; i < 4; ++i) {
    int gr = row0 + (tr << 2) + i;
    if (gr >= M) continue;
#pragma unroll
    for (int jj = 0; jj < 4; ++jj)
      C[(size_t)gr * ldc + col0 + (tc << 2) + jj] = acc[i][jj];
  }
}

// ---------------- strided copy ----------------
__global__ void copy_strided(const float* __restrict__ src, float* __restrict__ dst,
                             int n, int cshift, int cmask, int ldd) {
  int idx = blockIdx.x * 256 + threadIdx.x;
  if (idx >= n) return;
  int r = idx >> cshift, c = idx & cmask;
  dst[(size_t)r * ldd + c] = src[idx];
}

// ---------------- A-resident MFMA GEMM (256 thr, 4 waves, full residency) ----------------
// MODE 0: A = (Ah,Al) bf16 pair.
// MODE 1: A = split(relu(G*sc+sh) + (Rh+Rl))
// MODE 2: A = split(relu(G*sc+sh) + b2f(ucat[.,256+c]))
#define LOADB(ntv, ktv, BH, BL)                                     \
  {                                                                 \
    int n_ = (ntv) * 64 + w * 16 + lm;                              \
    _Pragma("unroll") for (int ks = 0; ks < 2; ++ks) {              \
      int kc = (ktv) * 8 + ks * 4 + lg;                             \
      size_t o = ((size_t)kc * N + n_) * 8;                         \
      BH[ks] = *reinterpret_cast<const short8v*>(Bh + o);           \
      BL[ks] = *reinterpret_cast<const short8v*>(Bl + o);           \
    }                                                               \
  }

template <int MODE>
__global__ __launch_bounds__(256) void gemm_fused(const short* __restrict__ Ah,
                                                  const short* __restrict__ Al,
                                                  const float* __restrict__ Gsrc,
                                                  const float* __restrict__ scshp,
                                                  const short* __restrict__ Rh,
                                                  const short* __restrict__ Rl,
                                                  const unsigned short* __restrict__ ures,
                                                  const short* __restrict__ Bh,
                                                  const short* __restrict__ Bl,
                                                  unsigned short* __restrict__ C,
                                                  const float* __restrict__ bias,
                                                  int M, int N, int ldc) {
  __shared__ __align__(16) short lds[16384];  // hi [0,8192), lo [8192,16384) shorts
  const int K = 256;
  int tid = threadIdx.x;
  int w = tid >> 6, l = tid & 63;    // 4 waves
  int row0 = blockIdx.x * 32;
  int lm = l & 15, lg = l >> 4;

#pragma unroll
  for (int i = 0; i < 4; ++i) {
    int id = i * 256 + tid;          // 1024 16B-chunks per half
    int r = id >> 5, c = id & 31;
    int gr = row0 + r; if (gr >= M) gr = M - 1;
    int sw = c ^ r;
    if (MODE == 0) {
      *reinterpret_cast<float4*>(lds + r * 256 + sw * 8) =
          *reinterpret_cast<const float4*>(Ah + (size_t)gr * K + c * 8);
      *reinterpret_cast<float4*>(lds + 8192 + r * 256 + sw * 8) =
          *reinterpret_cast<const float4*>(Al + (size_t)gr * K + c * 8);
    } else {
      const float* gp = Gsrc + (size_t)gr * 256 + c * 8;
      float4 g0 = *reinterpret_cast<const float4*>(gp);
      float4 g1 = *reinterpret_cast<const float4*>(gp + 4);
      float4 sc0 = *reinterpret_cast<const float4*>(scshp + c * 8);
      float4 sc1 = *reinterpret_cast<const float4*>(scshp + c * 8 + 4);
      float4 sh0 = *reinterpret_cast<const float4*>(scshp + 256 + c * 8);
      float4 sh1 = *reinterpret_cast<const float4*>(scshp + 256 + c * 8 + 4);
      float vals[8] = {g0.x * sc0.x + sh0.x, g0.y * sc0.y + sh0.y,
                       g0.z * sc0.z + sh0.z, g0.w * sc0.w + sh0.w,
                       g1.x * sc1.x + sh1.x, g1.y * sc1.y + sh1.y,
                       g1.z * sc1.z + sh1.z, g1.w * sc1.w + sh1.w};
      float res[8];
      if (MODE == 1) {
        short8v hv = *reinterpret_cast<const short8v*>(Rh + (size_t)gr * 256 + c * 8);
        short8v lv = *reinterpret_cast<const short8v*>(Rl + (size_t)gr * 256 + c * 8);
#pragma unroll
        for (int j = 0; j < 8; ++j)
          res[j] = b2f((unsigned short)hv[j]) + b2f((unsigned short)lv[j]);
      } else {
        short8v uv = *reinterpret_cast<const short8v*>(
            (const short*)ures + (size_t)gr * 512 + 256 + c * 8);
#pragma unroll
        for (int j = 0; j < 8; ++j) res[j] = b2f((unsigned short)uv[j]);
      }
      short8v hs, ls;
#pragma unroll
      for (int j = 0; j < 8; ++j) {
        float y = fmaxf(vals[j], 0.f) + res[j];
        unsigned short h = f2bs(y);
        hs[j] = (short)h;
        ls[j] = (short)f2bs(y - b2f(h));
      }
      *reinterpret_cast<short8v*>(lds + r * 256 + sw * 8) = hs;
      *reinterpret_cast<short8v*>(lds + 8192 + r * 256 + sw * 8) = ls;
    }
  }
  __syncthreads();

  int NT = N >> 6;  // 64-col slices (4 waves x 16)
  short8v bhX[2], blX[2], bhY[2], blY[2];
  LOADB(0, 0, bhX, blX);
  for (int nt = 0; nt < NT; ++nt) {
    float4v acc[2] = {};
    int n = nt * 64 + w * 16 + lm;
#pragma unroll
    for (int kt = 0; kt < 4; ++kt) {
      int nt_n = (kt == 3) ? ((nt + 1 < NT) ? nt + 1 : nt) : nt;
      int kt_n = (kt + 1) & 3;
      short8v a_h[2][2], a_l[2][2];
#pragma unroll
      for (int mf = 0; mf < 2; ++mf)
#pragma unroll
        for (int ks = 0; ks < 2; ++ks) {
          int r = mf * 16 + lm;
          int c = kt * 8 + ks * 4 + lg;
          int sw = c ^ r;
          a_h[mf][ks] = *reinterpret_cast<const short8v*>(lds + r * 256 + sw * 8);
          a_l[mf][ks] = *reinterpret_cast<const short8v*>(lds + 8192 + r * 256 + sw * 8);
        }
      if ((kt & 1) == 0) {
        LOADB(nt_n, kt_n, bhY, blY);
#pragma unroll
        for (int mf = 0; mf < 2; ++mf)
#pragma unroll
          for (int ks = 0; ks < 2; ++ks) {
            acc[mf] = __builtin_amdgcn_mfma_f32_16x16x32_bf16(a_h[mf][ks], bhX[ks], acc[mf], 0, 0, 0);
            acc[mf] = __builtin_amdgcn_mfma_f32_16x16x32_bf16(a_h[mf][ks], blX[ks], acc[mf], 0, 0, 0);
            acc[mf] = __builtin_amdgcn_mfma_f32_16x16x32_bf16(a_l[mf][ks], bhX[ks], acc[mf], 0, 0, 0);
          }
      } else {
        LOADB(nt_n, kt_n, bhX, blX);
#pragma unroll
        for (int mf = 0; mf < 2; ++mf)
#pragma unroll
          for (int ks = 0; ks < 2; ++ks) {
            acc[mf] = __builtin_amdgcn_mfma_f32_16x16x32_bf16(a_h[mf][ks], bhY[ks], acc[mf], 0, 0, 0);
            acc[mf] = __builtin_amdgcn_mfma_f32_16x16x32_bf16(a_h[mf][ks], blY[ks], acc[mf], 0, 0, 0);
            acc[mf] = __builtin_amdgcn_mfma_f32_16x16x32_bf16(a_l[mf][ks], bhY[ks], acc[mf], 0, 0, 0);
          }
      }
    }
    float bb = bias ? bias[n] : 0.f;
#pragma unroll
    for (int mf = 0; mf < 2; ++mf)
#pragma unroll
      for (int r = 0; r < 4; ++r) {
        int m = row0 + mf * 16 + lg * 4 + r;
        if (m < M) C[(size_t)m * ldc + n] = f2bs(acc[mf][r] + bb);
      }
  }
}

// ---------------- CSR gather (one node per 64-thread block), int2 CSR, bf16 U ----------------
__global__ void agg_kernel(const unsigned short* __restrict__ U, int ldu,
                           const int* __restrict__ rowptr, const int2* __restrict__ csr,
                           const float* __restrict__ sarr, const float* __restrict__ V,
                           float* __restrict__ G) {
  int i = blockIdx.x, t = threadIdx.x;  // t in [0,64)
  float s = sarr[i];
  float4 v4 = ((const float4*)V)[t];
  float ax = s * v4.x, ay = s * v4.y, az = s * v4.z, aw = s * v4.w;
  int p1 = rowptr[i + 1];
  for (int p = rowptr[i]; p < p1; ++p) {
    int2 e = csr[p];
    float c = __int_as_float(e.y);
    ushort4 u4 = *reinterpret_cast<const ushort4*>(U + (size_t)e.x * ldu + (t << 2));
    ax += c * b2f(u4.x); ay += c * b2f(u4.y); az += c * b2f(u4.z); aw += c * b2f(u4.w);
  }
  *reinterpret_cast<float4*>(G + (size_t)i * 256 + (t << 2)) = make_float4(ax, ay, az, aw);
}

// ---------------- BN stats: 64-row blocks, float4 lanes, LDS cross-team reduce ----------------
__global__ void colpart_kernel(const float* __restrict__ h, float* __restrict__ part, int F) {
  __shared__ float4 sm0[256], sm1[256];
  int t = threadIdx.x;
  int cols4 = F >> 2;
  int lc = t & (cols4 - 1);
  int team = t / cols4;
  int rpi = 256 / cols4;
  int r0 = blockIdx.x * 64;
  int r1 = min(r0 + 64, NN);
  float4 s0 = make_float4(0.f, 0.f, 0.f, 0.f);
  float4 s1 = make_float4(0.f, 0.f, 0.f, 0.f);
  for (int r = r0 + team; r < r1; r += rpi) {
    float4 x = *reinterpret_cast<const float4*>(h + (size_t)r * F + lc * 4);
    s0.x += x.x; s0.y += x.y; s0.z += x.z; s0.w += x.w;
    s1.x += x.x * x.x; s1.y += x.y * x.y; s1.z += x.z * x.z; s1.w += x.w * x.w;
  }
  sm0[t] = s0; sm1[t] = s1;
  __syncthreads();
  if (team == 0) {
    for (int k = 1; k < rpi; ++k) {
      float4 a = sm0[k * cols4 + lc];
      float4 b = sm1[k * cols4 + lc];
      s0.x += a.x; s0.y += a.y; s0.z += a.z; s0.w += a.w;
      s1.x += b.x; s1.y += b.y; s1.z += b.z; s1.w += b.w;
    }
    *reinterpret_cast<float4*>(part + (size_t)blockIdx.x * 2 * F + lc * 4) = s0;
    *reinterpret_cast<float4*>(part + (size_t)blockIdx.x * 2 * F + F + lc * 4) = s1;
  }
}

// parallel partial reduce: part[nb][F2] -> part2[8][F2]
__global__ void bnred_kernel(const float* __restrict__ part, float* __restrict__ part2,
                             int F2, int nb) {
  int c = blockIdx.x * 256 + threadIdx.x;
  if (c >= F2) return;
  int chunk = blockIdx.y;
  int cs = (nb + 7) >> 3;
  int b0 = chunk * cs;
  int b1 = min(b0 + cs, nb);
  float s0 = 0.f, s1 = 0.f, s2 = 0.f, s3 = 0.f;
  int b = b0;
  for (; b + 3 < b1; b += 4) {
    s0 += part[(size_t)(b + 0) * F2 + c];
    s1 += part[(size_t)(b + 1) * F2 + c];
    s2 += part[(size_t)(b + 2) * F2 + c];
    s3 += part[(size_t)(b + 3) * F2 + c];
  }
  for (; b < b1; ++b) s0 += part[(size_t)b * F2 + c];
  part2[(size_t)chunk * F2 + c] = (s0 + s1) + (s2 + s3);
}

__global__ void bnfin_kernel(const float* __restrict__ part2, const float* __restrict__ gamma,
                             const float* __restrict__ beta, int F,
                             float* __restrict__ scsh) {
  int t = threadIdx.x;
  int F2 = 2 * F;
  float s0 = 0.f, s1 = 0.f;
#pragma unroll
  for (int b = 0; b < 8; ++b) {
    s0 += part2[(size_t)b * F2 + t];
    s1 += part2[(size_t)b * F2 + F + t];
  }
  const float invn = 1.f / (float)NN;
  float m = s0 * invn;
  float var = s1 * invn - m * m;
  float sc = gamma[t] * rsqrtf(var + 1e-5f);
  scsh[t] = sc;
  scsh[F + t] = beta[t] - m * sc;
}

// analytic BN-of-BN for logstd cols (128..255 of G)
__global__ void bnfin2_kernel(const float* __restrict__ part2, const float* __restrict__ scsh,
                              const float* __restrict__ gamma2, const float* __restrict__ beta2,
                              float* __restrict__ ab) {
  int t = threadIdx.x;  // 0..127
  int c = 128 + t;
  float s0 = 0.f, s1 = 0.f;
#pragma unroll
  for (int b = 0; b < 8; ++b) {
    s0 += part2[(size_t)b * 512 + c];
    s1 += part2[(size_t)b * 512 + 256 + c];
  }
  const float invn = 1.f / (float)NN;
  float m_g = s0 * invn;
  float v_g = s1 * invn - m_g * m_g;
  float sc1 = scsh[c];
  float sh1 = scsh[256 + c];
  float m_L = m_g * sc1 + sh1;
  float v_L = v_g * sc1 * sc1;
  float sc2 = gamma2[t] * rsqrtf(v_L + 1e-5f);
  float sh2 = beta2[t] - m_L * sc2;
  ab[t] = sc1 * (1.f + sc2);
  ab[128 + t] = sh1 * (1.f + sc2) + sh2;
}

// ---------------- merged output epilogue: mean (cols 0..127) + logstd (cols 128..255) ----------------
__global__ void apply_out_kernel(const float* __restrict__ g, const float* __restrict__ scsh,
                                 const float* __restrict__ ab,
                                 const unsigned short* __restrict__ ucat,
                                 float* __restrict__ out_mean, float* __restrict__ out_logstd,
                                 int n) {
  int idx = blockIdx.x * 256 + threadIdx.x;
  if (idx >= n) return;
  int r = idx >> 8, c = idx & 255;
  float v = g[idx];
  if (c < 128) {
    out_mean[(size_t)r * 128 + c] = v * scsh[c] + scsh[256 + c] + b2f(ucat[(size_t)r * 384 + 256 + c]);
  } else {
    int cc = c - 128;
    out_logstd[(size_t)r * 128 + cc] = v * ab[cc] + ab[128 + cc];
  }
}

// ---------------- host-side failure codes ----------------
__global__ void write_code(float* __restrict__ out, float code) {
  int i = blockIdx.x * 256 + threadIdx.x;
  if (i < 4096) out[i] = code;
}

// ---------------- launch ----------------
extern "C" void kernel_launch(void* const* d_in, const int* in_sizes, int n_in,
                              void* d_out, int out_size, void* d_ws, size_t ws_size,
                              hipStream_t stream) {
  float* out_mean = (float*)d_out;
  float* out_logstd = out_mean + (size_t)NN * 128;

  static const int expect[35] = {5120000, 640000, 320000,
                                 65536, 64, 81920, 256,  65536, 64, 81920, 256,
                                 16384, 64, 24576, 128,  16384, 64, 24576, 128,
                                 65536, 256, 32768, 128, 65536, 256, 32768, 128,
                                 256, 256, 256, 256, 128, 128, 128, 128};
  if (n_in != 35) { write_code<<<16, 256, 0, stream>>>(out_mean, 900.f); return; }
  if (out_size != 5120000) { write_code<<<16, 256, 0, stream>>>(out_mean, 950.f); return; }
  for (int i = 0; i < 35; ++i)
    if (in_sizes[i] != expect[i]) {
      write_code<<<16, 256, 0, stream>>>(out_mean, 1000.f + 10.f * i);
      return;
    }

  const int* ei = (const int*)d_in[1];

  char* w = (char*)d_ws;
  size_t off = 0;
  auto alloc = [&](size_t bytes) -> void* {
    void* p = w + off;
    off += (bytes + 255) & ~(size_t)255;
    return p;
  };
  int* flag = (int*)alloc(4);
  int* cnt = (int*)alloc(NN * 4);
  int* rowptr = (int*)alloc((NN + 1) * 4);
  int* bsum = (int*)alloc(128 * 4);
  int* spart = (int*)alloc(NN * 4);
  int2* csr = (int2*)alloc((size_t)ET * 8);
  float* dis = (float*)alloc(NN * 4);
  float* sarr = (float*)alloc(NN * 4);
  float* Wf = (float*)alloc((size_t)576000 * 4);
  float* W1 = (float*)alloc((size_t)65536 * 4);
  float* W2cat = (float*)alloc((size_t)131072 * 4);
  float* W3cat = (float*)alloc((size_t)98304 * 4);
  float* WCa = (float*)alloc((size_t)65536 * 4);
  float* WCb = (float*)alloc((size_t)16384 * 4);
  float* WCc = (float*)alloc((size_t)16384 * 4);
  float* bias2 = (float*)alloc(512 * 4);
  float* bias3 = (float*)alloc(384 * 4);
  float* V1 = (float*)alloc(256 * 4);
  float* V2 = (float*)alloc(256 * 4);
  float* Vcat3 = (float*)alloc(256 * 4);
  float* Gpart = (float*)alloc((size_t)313 * 512 * 4);
  float* Gpart2 = (float*)alloc((size_t)8 * 512 * 4);
  float* scsh = (float*)alloc(512 * 4);
  float* ab = (float*)alloc(256 * 4);
  short* Bh1 = (short*)alloc((size_t)256 * 256 * 2);
  short* Bl1 = (short*)alloc((size_t)256 * 256 * 2);
  short* Bh2 = (short*)alloc((size_t)512 * 256 * 2);
  short* Bl2 = (short*)alloc((size_t)512 * 256 * 2);
  short* Bh3 = (short*)alloc((size_t)384 * 256 * 2);
  short* Bl3 = (short*)alloc((size_t)384 * 256 * 2);
  float* Gbuf = (float*)alloc((size_t)NN * 256 * 4);     // G (all three convs)
  float* regB = (float*)alloc((size_t)NN * 256 * 4);     // U1(bf16) -> U3cat(bf16, ld 384)
  float* regC = (float*)alloc((size_t)NN * 256 * 4);     // Xh/Xl (input hi/lo, live to gemm2)
  float* Ucat = (float*)alloc((size_t)NN * 512 * 4);     // U2cat (bf16, ld 512)
  if (off > ws_size) { write_code<<<16, 256, 0, stream>>>(out_mean, 2000.f); return; }

  unsigned short* U1 = (unsigned short*)regB;
  unsigned short* U3 = (unsigned short*)regB;           // U3cat ld 384 (U1 dead after agg1)
  short* Xh = (short*)regC;
  short* Xl = Xh + (size_t)NN * 256;
  float* G = Gbuf;
  unsigned short* U2 = (unsigned short*)Ucat;           // U2cat ld 512

  const int n256 = NN * 256, n128 = NN * 128;
  const int g256 = (n256 + 255) / 256;
  const int nb = (NN + 255) / 256;   // 79 (scan)
  const int nbc = (NN + 63) / 64;    // 313 (colpart)

  // ---- dtype + converts ----
  detect_kernel<<<1, 256, 0, stream>>>((const unsigned short*)d_in[0], flag);
  convert_x_kernel<<<(n256 / 4 + 255) / 256, 256, 0, stream>>>(d_in[0], Xh, Xl, n256 / 4, flag);

  WSpec wsp;
  const int map[28] = {3, 5, 7, 9, 11, 13, 15, 17, 4, 8, 12, 16, 19, 21, 23, 25,
                       20, 22, 24, 26, 27, 28, 29, 30, 31, 33, 32, 34};
  const int offs[28] = {0, 65536, 147456, 212992, 294912, 311296, 335872, 352256,
                        376832, 376896, 376960, 377024, 377088, 442624, 475392, 540928,
                        573696, 573952, 574080, 574336, 574464, 574720, 574976, 575232,
                        575488, 575616, 575744, 575872};
  const int lens[28] = {65536, 81920, 65536, 81920, 16384, 24576, 16384, 24576,
                        64, 64, 64, 64, 65536, 32768, 65536, 32768,
                        256, 128, 256, 128, 256, 256, 256, 256,
                        128, 128, 128, 128};
  for (int i = 0; i < 28; ++i) { wsp.p[i] = d_in[map[i]]; wsp.off[i] = offs[i]; wsp.len[i] = lens[i]; }
  convert_weights<<<dim3(28, 8), 256, 0, stream>>>(wsp, Wf, flag);

  // ---- graph prep ----
  hipMemsetAsync(cnt, 0, NN * 4, stream);
  count_kernel<<<(ET + 255) / 256, 256, 0, stream>>>(ei, cnt);
  dis_kernel<<<(NN + 255) / 256, 256, 0, stream>>>(cnt, dis);
  scan1_kernel<<<nb, 256, 0, stream>>>(cnt, spart, bsum);
  scan2_kernel<<<1, 128, 0, stream>>>(bsum, nb);
  scan3_kernel<<<nb, 256, 0, stream>>>(spart, bsum, rowptr);
  hipMemsetAsync(cnt, 0, NN * 4, stream);
  hipMemsetAsync(sarr, 0, NN * 4, stream);
  fill_kernel<<<(ET + 255) / 256, 256, 0, stream>>>(ei, d_in[2], dis, rowptr, cnt, csr, sarr, flag);

  // ---- weight prep stage 1 ----
  {
    GJobs jb{};
    auto set = [&](int j, const float* A, const float* B, float* C, int M, int N, int K,
                   int ldc, int bx, int cum) {
      jb.A[j] = A; jb.B[j] = B; jb.C[j] = C; jb.M[j] = M; jb.N[j] = N; jb.K[j] = K;
      jb.ldc[j] = ldc; jb.blkx[j] = bx; jb.cum[j] = cum;
    };
    set(0, Wf + 0,      Wf + 65536,  W1,          256, 256, 256, 256, 4, 16);
    set(1, Wf + 147456, Wf + 212992, WCa,         256, 256, 256, 256, 4, 32);
    set(2, Wf + 294912, Wf + 311296, WCb,         128, 128, 128, 128, 2, 36);
    set(3, Wf + 335872, Wf + 352256, WCc,         128, 128, 128, 128, 2, 40);
    set(4, Wf + 376832, Wf + 131072, V1,          1,   256, 64,  256, 1, 44);
    set(5, Wf + 376896, Wf + 278528, V2,          1,   256, 64,  256, 1, 48);
    set(6, Wf + 376960, Wf + 327680, Vcat3,       1,   128, 64,  128, 1, 50);
    set(7, Wf + 377024, Wf + 368640, Vcat3 + 128, 1,   128, 64,  128, 1, 52);
    jb.njobs = 8;
    gemm64_multi<<<52, 256, 0, stream>>>(jb);
  }
  // ---- weight prep stage 2 ----
  {
    GJobs jb{};
    auto set = [&](int j, const float* A, const float* B, float* C, int M, int N, int K,
                   int ldc, int bx, int cum) {
      jb.A[j] = A; jb.B[j] = B; jb.C[j] = C; jb.M[j] = M; jb.N[j] = N; jb.K[j] = K;
      jb.ldc[j] = ldc; jb.blkx[j] = bx; jb.cum[j] = cum;
    };
    set(0, Wf + 377088, WCa, W2cat,       256, 256, 256, 512, 4, 16);
    set(1, Wf + 573696, WCa, bias2,       1,   256, 256, 512, 1, 20);
    set(2, Wf + 442624, WCb, W3cat,       256, 128, 128, 384, 4, 28);
    set(3, Wf + 442624, WCc, W3cat + 128, 256, 128, 128, 384, 4, 36);
    set(4, Wf + 573952, WCb, bias3,       1,   128, 128, 384, 1, 38);
    set(5, Wf + 573952, WCc, bias3 + 128, 1,   128, 128, 384, 1, 40);
    jb.njobs = 6;
    gemm64_multi<<<40, 256, 0, stream>>>(jb);
  }
  copy_strided<<<256, 256, 0, stream>>>(Wf + 475392, W2cat + 256, 65536, 8, 255, 512);
  copy_strided<<<1, 256, 0, stream>>>(Wf + 574080, bias2 + 256, 256, 8, 255, 512);
  copy_strided<<<128, 256, 0, stream>>>(Wf + 540928, W3cat + 256, 32768, 7, 127, 384);
  copy_strided<<<1, 256, 0, stream>>>(Wf + 574336, bias3 + 256, 128, 7, 127, 384);

  // ---- weight hi/lo k-chunked converts ----
  bconv_kernel<<<256, 256, 0, stream>>>(W1, 256, Bh1, Bl1, 256);
  bconv_kernel<<<512, 256, 0, stream>>>(W2cat, 512, Bh2, Bl2, 512);
  bconv_kernel<<<384, 256, 0, stream>>>(W3cat, 384, Bh3, Bl3, 384);

  // ---- conv1: U1 = X @ W1 ----
  gemm_fused<0><<<625, 256, 0, stream>>>(Xh, Xl, nullptr, nullptr, nullptr, nullptr, nullptr,
                                         Bh1, Bl1, U1, nullptr, NN, 256, 256);
  agg_kernel<<<NN, 64, 0, stream>>>(U1, 256, rowptr, csr, sarr, V1, G);
  colpart_kernel<<<nbc, 256, 0, stream>>>(G, Gpart, 256);
  bnred_kernel<<<dim3(2, 8), 256, 0, stream>>>(Gpart, Gpart2, 512, nbc);
  bnfin_kernel<<<1, 256, 0, stream>>>(Gpart2, Wf + 574464, Wf + 574720, 256, scsh);

  // ---- conv2 + pih: U2cat = x1 @ W2cat, x1 built in staging from G/scsh/X ----
  gemm_fused<1><<<625, 256, 0, stream>>>(nullptr, nullptr, G, scsh, Xh, Xl, nullptr,
                                         Bh2, Bl2, U2, bias2, NN, 512, 512);
  agg_kernel<<<NN, 64, 0, stream>>>(U2, 512, rowptr, csr, sarr, V2, G);
  colpart_kernel<<<nbc, 256, 0, stream>>>(G, Gpart, 256);
  bnred_kernel<<<dim3(2, 8), 256, 0, stream>>>(Gpart, Gpart2, 512, nbc);
  bnfin_kernel<<<1, 256, 0, stream>>>(Gpart2, Wf + 574976, Wf + 575232, 256, scsh);

  // ---- conv3 (mean|logstd|pho): U3cat = x2 @ W3cat, x2 built from G/scsh/U2 resid ----
  gemm_fused<2><<<625, 256, 0, stream>>>(nullptr, nullptr, G, scsh, nullptr, nullptr, U2,
                                         Bh3, Bl3, U3, bias3, NN, 384, 384);
  agg_kernel<<<NN, 64, 0, stream>>>(U3, 384, rowptr, csr, sarr, Vcat3, G);
  colpart_kernel<<<nbc, 256, 0, stream>>>(G, Gpart, 256);
  bnred_kernel<<<dim3(2, 8), 256, 0, stream>>>(Gpart, Gpart2, 512, nbc);
  bnfin_kernel<<<1, 256, 0, stream>>>(Gpart2, Wf + 575488, Wf + 575744, 256, scsh);
  bnfin2_kernel<<<1, 128, 0, stream>>>(Gpart2, scsh, Wf + 575616, Wf + 575872, ab);
  apply_out_kernel<<<g256, 256, 0, stream>>>(G, scsh, ab, U3, out_mean, out_logstd, n256);
}

// Round 20
// 369.751 us; speedup vs baseline: 1.0370x; 1.0370x over previous
//
#include <hip/hip_runtime.h>

#define NN 20000
#define EE 320000
#define ET (EE + NN)

typedef __attribute__((ext_vector_type(8))) short short8v;
typedef __attribute__((ext_vector_type(4))) float float4v;

__device__ __forceinline__ float b2f(unsigned short u) {
  union { float f; unsigned int i; } c; c.i = ((unsigned int)u) << 16; return c.f;
}
__device__ __forceinline__ unsigned short f2bs(float f) {  // f32 -> bf16 bits, RNE
  union { float f; unsigned int u; } c; c.f = f;
  unsigned int r = c.u + 0x7fffu + ((c.u >> 16) & 1u);
  return (unsigned short)(r >> 16);
}

// ---------------- input dtype detector (flag=1 -> f32, flag=0 -> bf16) ----------------
__global__ void detect_kernel(const unsigned short* __restrict__ x, int* __restrict__ flag) {
  __shared__ int cnt_s;
  if (threadIdx.x == 0) cnt_s = 0;
  __syncthreads();
  int pass = 0;
  for (int j = 0; j < 16; ++j) {
    unsigned short u = x[2 * (threadIdx.x * 16 + j)];
    int e = (u >> 7) & 0xFF;
    if (e >= 96 && e <= 150) pass++;
  }
  atomicAdd(&cnt_s, pass);
  __syncthreads();
  if (threadIdx.x == 0) *flag = (cnt_s < 2458) ? 1 : 0;
}

// x -> hi/lo bf16 (residual recovered as hi+lo; no f32 copy)
__global__ void convert_x_kernel(const void* __restrict__ in,
                                 short* __restrict__ xh, short* __restrict__ xl, int n4,
                                 const int* __restrict__ flag) {
  int i = blockIdx.x * 256 + threadIdx.x;
  if (i >= n4) return;
  float4 v;
  if (*flag) {
    v = ((const float4*)in)[i];
  } else {
    ushort4 u = ((const ushort4*)in)[i];
    v = make_float4(b2f(u.x), b2f(u.y), b2f(u.z), b2f(u.w));
  }
  ushort4 h, l;
  h.x = f2bs(v.x); l.x = f2bs(v.x - b2f(h.x));
  h.y = f2bs(v.y); l.y = f2bs(v.y - b2f(h.y));
  h.z = f2bs(v.z); l.z = f2bs(v.z - b2f(h.z));
  h.w = f2bs(v.w); l.w = f2bs(v.w - b2f(h.w));
  ((ushort4*)xh)[i] = h;
  ((ushort4*)xl)[i] = l;
}

struct WSpec { const void* p[28]; int off[28]; int len[28]; };
__global__ void convert_weights(WSpec ws, float* __restrict__ out, const int* __restrict__ flag) {
  int b = blockIdx.x;
  int f32m = *flag;
  const void* p = ws.p[b];
  int off = ws.off[b], len4 = ws.len[b] >> 2;
  float4* dst = (float4*)(out + off);
  for (int i = blockIdx.y * 256 + threadIdx.x; i < len4; i += 8 * 256) {
    if (f32m) {
      dst[i] = ((const float4*)p)[i];
    } else {
      ushort4 u = ((const ushort4*)p)[i];
      dst[i] = make_float4(b2f(u.x), b2f(u.y), b2f(u.z), b2f(u.w));
    }
  }
}

// W [K x N] row-major (ldb=N) -> k-chunked hi/lo bf16: element (n,k) at ((k>>3)*N+n)*8+(k&7)
__global__ void bconv_kernel(const float* __restrict__ W, int ldb,
                             short* __restrict__ Bh, short* __restrict__ Bl, int N) {
  int idx = blockIdx.x * 256 + threadIdx.x;
  if (idx >= N * 256) return;
  int n = idx >> 8, k = idx & 255;
  float v = W[(size_t)k * ldb + n];
  unsigned short h = f2bs(v);
  size_t o = ((size_t)(k >> 3) * N + n) * 8 + (k & 7);
  Bh[o] = (short)h;
  Bl[o] = (short)f2bs(v - b2f(h));
}

// ---------------- graph prep: degrees + CSR ----------------
__global__ void count_kernel(const int* __restrict__ ei, int* __restrict__ cnt) {
  int e = blockIdx.x * 256 + threadIdx.x;
  if (e >= ET) return;
  int dst = (e < EE) ? ei[EE + e] : (e - EE);
  atomicAdd(&cnt[dst], 1);
}

// scan1 + dis fused (dis[i] = rsqrt(cnt[i]+1e-6))
__global__ void scan1_kernel(const int* __restrict__ cnt, int* __restrict__ partial,
                             int* __restrict__ bsum, float* __restrict__ dis) {
  __shared__ int sd[256];
  int b = blockIdx.x, t = threadIdx.x;
  int i = b * 256 + t;
  int v = (i < NN) ? cnt[i] : 0;
  if (i < NN) dis[i] = rsqrtf((float)v + 1e-6f);
  sd[t] = v;
  __syncthreads();
  for (int off = 1; off < 256; off <<= 1) {
    int x = (t >= off) ? sd[t - off] : 0;
    __syncthreads();
    sd[t] += x;
    __syncthreads();
  }
  if (i < NN) partial[i] = sd[t];
  if (t == 255) bsum[b] = sd[255];
}

__global__ void scan2_kernel(int* __restrict__ bsum, int nb) {
  __shared__ int sd[128];
  int t = threadIdx.x;
  sd[t] = (t < nb) ? bsum[t] : 0;
  __syncthreads();
  for (int off = 1; off < 128; off <<= 1) {
    int x = (t >= off) ? sd[t - off] : 0;
    __syncthreads();
    sd[t] += x;
    __syncthreads();
  }
  if (t < nb) bsum[t] = sd[t];
}

__global__ void scan3_kernel(const int* __restrict__ partial, const int* __restrict__ bsum,
                             int* __restrict__ rowptr) {
  int i = blockIdx.x * 256 + threadIdx.x;
  if (i == 0) rowptr[0] = 0;
  if (i < NN) {
    int b = i >> 8;
    rowptr[i + 1] = partial[i] + (b ? bsum[b - 1] : 0);
  }
}

// packed CSR entry: .x = src, .y = coef bits; edge_attr read raw with dtype flag
__global__ void fill_kernel(const int* __restrict__ ei, const void* __restrict__ ea,
                            const float* __restrict__ dis, const int* __restrict__ rowptr,
                            int* __restrict__ cursor, int2* __restrict__ csr,
                            float* __restrict__ sarr, const int* __restrict__ flag) {
  int e = blockIdx.x * 256 + threadIdx.x;
  if (e >= ET) return;
  int src, dst; float a;
  if (e < EE) {
    src = ei[e]; dst = ei[EE + e];
    a = (*flag) ? ((const float*)ea)[e] : b2f(((const unsigned short*)ea)[e]);
  } else {
    src = dst = e - EE; a = 0.f;
  }
  float coef = dis[src] * dis[dst];
  int pos = rowptr[dst] + atomicAdd(&cursor[dst], 1);
  csr[pos] = make_int2(src, __float_as_int(coef));
  if (a != 0.f) atomicAdd(&sarr[dst], coef * a);
}

// ---------------- batched small GEMMs (64x64 tile, 4x4 micro) ----------------
struct GJobs {
  const float* A[8]; const float* B[8]; float* C[8];
  int M[8], N[8], K[8], ldc[8], blkx[8], cum[8];
  int njobs;
};
__global__ __launch_bounds__(256) void gemm64_multi(GJobs jb) {
  int bid = blockIdx.x;
  int j = 0;
  while (j < jb.njobs - 1 && bid >= jb.cum[j]) ++j;
  int local = bid - (j ? jb.cum[j - 1] : 0);
  const float* A = jb.A[j];
  const float* B = jb.B[j];
  float* C = jb.C[j];
  int M = jb.M[j], N = jb.N[j], K = jb.K[j], ldc = jb.ldc[j];
  int bx = local % jb.blkx[j], by = local / jb.blkx[j];

  __shared__ float As[16][68];
  __shared__ float Bs[16][64];
  int tid = threadIdx.x;
  int row0 = bx * 64, col0 = by * 64;
  int tr = tid >> 4, tc = tid & 15;
  float acc[4][4] = {};
  int lmA = tid >> 2;
  int lkA = (tid & 3) << 2;
  int lkB = tid >> 4;
  int lcB = (tid & 15) << 2;
  for (int k0 = 0; k0 < K; k0 += 16) {
    int gr = row0 + lmA;
    float4 a4 = make_float4(0.f, 0.f, 0.f, 0.f);
    if (gr < M) a4 = *reinterpret_cast<const float4*>(&A[(size_t)gr * K + k0 + lkA]);
    As[lkA + 0][lmA] = a4.x;
    As[lkA + 1][lmA] = a4.y;
    As[lkA + 2][lmA] = a4.z;
    As[lkA + 3][lmA] = a4.w;
    float4 b4 = *reinterpret_cast<const float4*>(&B[(size_t)(k0 + lkB) * N + col0 + lcB]);
    *reinterpret_cast<float4*>(&Bs[lkB][lcB]) = b4;
    __syncthreads();
#pragma unroll
    for (int kk = 0; kk < 16; ++kk) {
      float4 av = *reinterpret_cast<const float4*>(&As[kk][tr << 2]);
      float4 bv = *reinterpret_cast<const float4*>(&Bs[kk][tc << 2]);
      float aa[4] = {av.x, av.y, av.z, av.w};
      float bb[4] = {bv.x, bv.y, bv.z, bv.w};
#pragma unroll
      for (int i = 0; i < 4; ++i)
#pragma unroll
        for (int jj = 0; jj < 4; ++jj) acc[i][jj] += aa[i] * bb[jj];
    }
    __syncthreads();
  }
#pragma unroll
  for (int i = 0; i < 4; ++i) {
    int gr = row0 + (tr << 2) + i;
    if (gr >= M) continue;
#pragma unroll
    for (int jj = 0; jj < 4; ++jj)
      C[(size_t)gr * ldc + col0 + (tc << 2) + jj] = acc[i][jj];
  }
}

// ---------------- strided copy ----------------
__global__ void copy_strided(const float* __restrict__ src, float* __restrict__ dst,
                             int n, int cshift, int cmask, int ldd) {
  int idx = blockIdx.x * 256 + threadIdx.x;
  if (idx >= n) return;
  int r = idx >> cshift, c = idx & cmask;
  dst[(size_t)r * ldd + c] = src[idx];
}

// ---------------- A-resident MFMA GEMM (512 thr, 8 waves) with fused staging ----------------
// MODE 0: A = (Ah,Al) bf16 pair.
// MODE 1: A = split(relu(G*sc+sh) + (Rh+Rl))
// MODE 2: A = split(relu(G*sc+sh) + b2f(ucat[.,256+c]))
#define LOADB(ntv, ktv, BH, BL)                                     \
  {                                                                 \
    int n_ = (ntv) * 128 + w * 16 + lm;                             \
    _Pragma("unroll") for (int ks = 0; ks < 2; ++ks) {              \
      int kc = (ktv) * 8 + ks * 4 + lg;                             \
      size_t o = ((size_t)kc * N + n_) * 8;                         \
      BH[ks] = *reinterpret_cast<const short8v*>(Bh + o);           \
      BL[ks] = *reinterpret_cast<const short8v*>(Bl + o);           \
    }                                                               \
  }

template <int MODE>
__global__ __launch_bounds__(512) void gemm_fused(const short* __restrict__ Ah,
                                                  const short* __restrict__ Al,
                                                  const float* __restrict__ Gsrc,
                                                  const float* __restrict__ scshp,
                                                  const short* __restrict__ Rh,
                                                  const short* __restrict__ Rl,
                                                  const unsigned short* __restrict__ ures,
                                                  const short* __restrict__ Bh,
                                                  const short* __restrict__ Bl,
                                                  unsigned short* __restrict__ C,
                                                  const float* __restrict__ bias,
                                                  int M, int N, int ldc) {
  __shared__ __align__(16) short lds[16384];  // hi [0,8192), lo [8192,16384) shorts
  const int K = 256;
  int tid = threadIdx.x;
  int w = tid >> 6, l = tid & 63;
  int row0 = blockIdx.x * 32;
  int lm = l & 15, lg = l >> 4;

#pragma unroll
  for (int i = 0; i < 2; ++i) {
    int id = i * 512 + tid;
    int r = id >> 5, c = id & 31;
    int gr = row0 + r; if (gr >= M) gr = M - 1;
    int sw = c ^ r;
    if (MODE == 0) {
      *reinterpret_cast<float4*>(lds + r * 256 + sw * 8) =
          *reinterpret_cast<const float4*>(Ah + (size_t)gr * K + c * 8);
      *reinterpret_cast<float4*>(lds + 8192 + r * 256 + sw * 8) =
          *reinterpret_cast<const float4*>(Al + (size_t)gr * K + c * 8);
    } else {
      const float* gp = Gsrc + (size_t)gr * 256 + c * 8;
      float4 g0 = *reinterpret_cast<const float4*>(gp);
      float4 g1 = *reinterpret_cast<const float4*>(gp + 4);
      float4 sc0 = *reinterpret_cast<const float4*>(scshp + c * 8);
      float4 sc1 = *reinterpret_cast<const float4*>(scshp + c * 8 + 4);
      float4 sh0 = *reinterpret_cast<const float4*>(scshp + 256 + c * 8);
      float4 sh1 = *reinterpret_cast<const float4*>(scshp + 256 + c * 8 + 4);
      float vals[8] = {g0.x * sc0.x + sh0.x, g0.y * sc0.y + sh0.y,
                       g0.z * sc0.z + sh0.z, g0.w * sc0.w + sh0.w,
                       g1.x * sc1.x + sh1.x, g1.y * sc1.y + sh1.y,
                       g1.z * sc1.z + sh1.z, g1.w * sc1.w + sh1.w};
      float res[8];
      if (MODE == 1) {
        short8v hv = *reinterpret_cast<const short8v*>(Rh + (size_t)gr * 256 + c * 8);
        short8v lv = *reinterpret_cast<const short8v*>(Rl + (size_t)gr * 256 + c * 8);
#pragma unroll
        for (int j = 0; j < 8; ++j)
          res[j] = b2f((unsigned short)hv[j]) + b2f((unsigned short)lv[j]);
      } else {
        short8v uv = *reinterpret_cast<const short8v*>(
            (const short*)ures + (size_t)gr * 512 + 256 + c * 8);
#pragma unroll
        for (int j = 0; j < 8; ++j) res[j] = b2f((unsigned short)uv[j]);
      }
      short8v hs, ls;
#pragma unroll
      for (int j = 0; j < 8; ++j) {
        float y = fmaxf(vals[j], 0.f) + res[j];
        unsigned short h = f2bs(y);
        hs[j] = (short)h;
        ls[j] = (short)f2bs(y - b2f(h));
      }
      *reinterpret_cast<short8v*>(lds + r * 256 + sw * 8) = hs;
      *reinterpret_cast<short8v*>(lds + 8192 + r * 256 + sw * 8) = ls;
    }
  }
  __syncthreads();

  int NT = N >> 7;
  short8v bhX[2], blX[2], bhY[2], blY[2];
  LOADB(0, 0, bhX, blX);
  for (int nt = 0; nt < NT; ++nt) {
    float4v acc[2] = {};
    int n = nt * 128 + w * 16 + lm;
#pragma unroll
    for (int kt = 0; kt < 4; ++kt) {
      int nt_n = (kt == 3) ? ((nt + 1 < NT) ? nt + 1 : nt) : nt;
      int kt_n = (kt + 1) & 3;
      short8v a_h[2][2], a_l[2][2];
#pragma unroll
      for (int mf = 0; mf < 2; ++mf)
#pragma unroll
        for (int ks = 0; ks < 2; ++ks) {
          int r = mf * 16 + lm;
          int c = kt * 8 + ks * 4 + lg;
          int sw = c ^ r;
          a_h[mf][ks] = *reinterpret_cast<const short8v*>(lds + r * 256 + sw * 8);
          a_l[mf][ks] = *reinterpret_cast<const short8v*>(lds + 8192 + r * 256 + sw * 8);
        }
      if ((kt & 1) == 0) {
        LOADB(nt_n, kt_n, bhY, blY);
#pragma unroll
        for (int mf = 0; mf < 2; ++mf)
#pragma unroll
          for (int ks = 0; ks < 2; ++ks) {
            acc[mf] = __builtin_amdgcn_mfma_f32_16x16x32_bf16(a_h[mf][ks], bhX[ks], acc[mf], 0, 0, 0);
            acc[mf] = __builtin_amdgcn_mfma_f32_16x16x32_bf16(a_h[mf][ks], blX[ks], acc[mf], 0, 0, 0);
            acc[mf] = __builtin_amdgcn_mfma_f32_16x16x32_bf16(a_l[mf][ks], bhX[ks], acc[mf], 0, 0, 0);
          }
      } else {
        LOADB(nt_n, kt_n, bhX, blX);
#pragma unroll
        for (int mf = 0; mf < 2; ++mf)
#pragma unroll
          for (int ks = 0; ks < 2; ++ks) {
            acc[mf] = __builtin_amdgcn_mfma_f32_16x16x32_bf16(a_h[mf][ks], bhY[ks], acc[mf], 0, 0, 0);
            acc[mf] = __builtin_amdgcn_mfma_f32_16x16x32_bf16(a_h[mf][ks], blY[ks], acc[mf], 0, 0, 0);
            acc[mf] = __builtin_amdgcn_mfma_f32_16x16x32_bf16(a_l[mf][ks], bhY[ks], acc[mf], 0, 0, 0);
          }
      }
    }
    float bb = bias ? bias[n] : 0.f;
#pragma unroll
    for (int mf = 0; mf < 2; ++mf)
#pragma unroll
      for (int r = 0; r < 4; ++r) {
        int m = row0 + mf * 16 + lg * 4 + r;
        if (m < M) C[(size_t)m * ldc + n] = f2bs(acc[mf][r] + bb);
      }
  }
}

// ---------------- CSR gather (one node per 64-thread block), int2 CSR, bf16 U ----------------
__global__ void agg_kernel(const unsigned short* __restrict__ U, int ldu,
                           const int* __restrict__ rowptr, const int2* __restrict__ csr,
                           const float* __restrict__ sarr, const float* __restrict__ V,
                           float* __restrict__ G) {
  int i = blockIdx.x, t = threadIdx.x;  // t in [0,64)
  float s = sarr[i];
  float4 v4 = ((const float4*)V)[t];
  float ax = s * v4.x, ay = s * v4.y, az = s * v4.z, aw = s * v4.w;
  int p1 = rowptr[i + 1];
  for (int p = rowptr[i]; p < p1; ++p) {
    int2 e = csr[p];
    float c = __int_as_float(e.y);
    ushort4 u4 = *reinterpret_cast<const ushort4*>(U + (size_t)e.x * ldu + (t << 2));
    ax += c * b2f(u4.x); ay += c * b2f(u4.y); az += c * b2f(u4.z); aw += c * b2f(u4.w);
  }
  *reinterpret_cast<float4*>(G + (size_t)i * 256 + (t << 2)) = make_float4(ax, ay, az, aw);
}

// ---------------- BN stats: 64-row blocks, float4 lanes, LDS cross-team reduce ----------------
__global__ void colpart_kernel(const float* __restrict__ h, float* __restrict__ part, int F) {
  __shared__ float4 sm0[256], sm1[256];
  int t = threadIdx.x;
  int cols4 = F >> 2;
  int lc = t & (cols4 - 1);
  int team = t / cols4;
  int rpi = 256 / cols4;
  int r0 = blockIdx.x * 64;
  int r1 = min(r0 + 64, NN);
  float4 s0 = make_float4(0.f, 0.f, 0.f, 0.f);
  float4 s1 = make_float4(0.f, 0.f, 0.f, 0.f);
  for (int r = r0 + team; r < r1; r += rpi) {
    float4 x = *reinterpret_cast<const float4*>(h + (size_t)r * F + lc * 4);
    s0.x += x.x; s0.y += x.y; s0.z += x.z; s0.w += x.w;
    s1.x += x.x * x.x; s1.y += x.y * x.y; s1.z += x.z * x.z; s1.w += x.w * x.w;
  }
  sm0[t] = s0; sm1[t] = s1;
  __syncthreads();
  if (team == 0) {
    for (int k = 1; k < rpi; ++k) {
      float4 a = sm0[k * cols4 + lc];
      float4 b = sm1[k * cols4 + lc];
      s0.x += a.x; s0.y += a.y; s0.z += a.z; s0.w += a.w;
      s1.x += b.x; s1.y += b.y; s1.z += b.z; s1.w += b.w;
    }
    *reinterpret_cast<float4*>(part + (size_t)blockIdx.x * 2 * F + lc * 4) = s0;
    *reinterpret_cast<float4*>(part + (size_t)blockIdx.x * 2 * F + F + lc * 4) = s1;
  }
}

// parallel partial reduce: part[nb][F2] -> part2[8][F2]
__global__ void bnred_kernel(const float* __restrict__ part, float* __restrict__ part2,
                             int F2, int nb) {
  int c = blockIdx.x * 256 + threadIdx.x;
  if (c >= F2) return;
  int chunk = blockIdx.y;
  int cs = (nb + 7) >> 3;
  int b0 = chunk * cs;
  int b1 = min(b0 + cs, nb);
  float s0 = 0.f, s1 = 0.f, s2 = 0.f, s3 = 0.f;
  int b = b0;
  for (; b + 3 < b1; b += 4) {
    s0 += part[(size_t)(b + 0) * F2 + c];
    s1 += part[(size_t)(b + 1) * F2 + c];
    s2 += part[(size_t)(b + 2) * F2 + c];
    s3 += part[(size_t)(b + 3) * F2 + c];
  }
  for (; b < b1; ++b) s0 += part[(size_t)b * F2 + c];
  part2[(size_t)chunk * F2 + c] = (s0 + s1) + (s2 + s3);
}

__global__ void bnfin_kernel(const float* __restrict__ part2, const float* __restrict__ gamma,
                             const float* __restrict__ beta, int F,
                             float* __restrict__ scsh) {
  int t = threadIdx.x;
  int F2 = 2 * F;
  float s0 = 0.f, s1 = 0.f;
#pragma unroll
  for (int b = 0; b < 8; ++b) {
    s0 += part2[(size_t)b * F2 + t];
    s1 += part2[(size_t)b * F2 + F + t];
  }
  const float invn = 1.f / (float)NN;
  float m = s0 * invn;
  float var = s1 * invn - m * m;
  float sc = gamma[t] * rsqrtf(var + 1e-5f);
  scsh[t] = sc;
  scsh[F + t] = beta[t] - m * sc;
}

// analytic BN-of-BN for logstd cols (128..255 of G)
__global__ void bnfin2_kernel(const float* __restrict__ part2, const float* __restrict__ scsh,
                              const float* __restrict__ gamma2, const float* __restrict__ beta2,
                              float* __restrict__ ab) {
  int t = threadIdx.x;  // 0..127
  int c = 128 + t;
  float s0 = 0.f, s1 = 0.f;
#pragma unroll
  for (int b = 0; b < 8; ++b) {
    s0 += part2[(size_t)b * 512 + c];
    s1 += part2[(size_t)b * 512 + 256 + c];
  }
  const float invn = 1.f / (float)NN;
  float m_g = s0 * invn;
  float v_g = s1 * invn - m_g * m_g;
  float sc1 = scsh[c];
  float sh1 = scsh[256 + c];
  float m_L = m_g * sc1 + sh1;
  float v_L = v_g * sc1 * sc1;
  float sc2 = gamma2[t] * rsqrtf(v_L + 1e-5f);
  float sh2 = beta2[t] - m_L * sc2;
  ab[t] = sc1 * (1.f + sc2);
  ab[128 + t] = sh1 * (1.f + sc2) + sh2;
}

// ---------------- merged output epilogue ----------------
__global__ void apply_out_kernel(const float* __restrict__ g, const float* __restrict__ scsh,
                                 const float* __restrict__ ab,
                                 const unsigned short* __restrict__ ucat,
                                 float* __restrict__ out_mean, float* __restrict__ out_logstd,
                                 int n) {
  int idx = blockIdx.x * 256 + threadIdx.x;
  if (idx >= n) return;
  int r = idx >> 8, c = idx & 255;
  float v = g[idx];
  if (c < 128) {
    out_mean[(size_t)r * 128 + c] = v * scsh[c] + scsh[256 + c] + b2f(ucat[(size_t)r * 384 + 256 + c]);
  } else {
    int cc = c - 128;
    out_logstd[(size_t)r * 128 + cc] = v * ab[cc] + ab[128 + cc];
  }
}

// ---------------- host-side failure codes ----------------
__global__ void write_code(float* __restrict__ out, float code) {
  int i = blockIdx.x * 256 + threadIdx.x;
  if (i < 4096) out[i] = code;
}

// ---------------- launch ----------------
extern "C" void kernel_launch(void* const* d_in, const int* in_sizes, int n_in,
                              void* d_out, int out_size, void* d_ws, size_t ws_size,
                              hipStream_t stream) {
  float* out_mean = (float*)d_out;
  float* out_logstd = out_mean + (size_t)NN * 128;

  static const int expect[35] = {5120000, 640000, 320000,
                                 65536, 64, 81920, 256,  65536, 64, 81920, 256,
                                 16384, 64, 24576, 128,  16384, 64, 24576, 128,
                                 65536, 256, 32768, 128, 65536, 256, 32768, 128,
                                 256, 256, 256, 256, 128, 128, 128, 128};
  if (n_in != 35) { write_code<<<16, 256, 0, stream>>>(out_mean, 900.f); return; }
  if (out_size != 5120000) { write_code<<<16, 256, 0, stream>>>(out_mean, 950.f); return; }
  for (int i = 0; i < 35; ++i)
    if (in_sizes[i] != expect[i]) {
      write_code<<<16, 256, 0, stream>>>(out_mean, 1000.f + 10.f * i);
      return;
    }

  const int* ei = (const int*)d_in[1];

  char* w = (char*)d_ws;
  size_t off = 0;
  auto alloc = [&](size_t bytes) -> void* {
    void* p = w + off;
    off += (bytes + 255) & ~(size_t)255;
    return p;
  };
  int* flag = (int*)alloc(4);
  int* cnt = (int*)alloc(NN * 4);
  int* rowptr = (int*)alloc((NN + 1) * 4);
  int* bsum = (int*)alloc(128 * 4);
  int* spart = (int*)alloc(NN * 4);
  int2* csr = (int2*)alloc((size_t)ET * 8);
  float* dis = (float*)alloc(NN * 4);
  float* sarr = (float*)alloc(NN * 4);
  float* Wf = (float*)alloc((size_t)576000 * 4);
  float* W1 = (float*)alloc((size_t)65536 * 4);
  float* W2cat = (float*)alloc((size_t)131072 * 4);
  float* W3cat = (float*)alloc((size_t)98304 * 4);
  float* WCa = (float*)alloc((size_t)65536 * 4);
  float* WCb = (float*)alloc((size_t)16384 * 4);
  float* WCc = (float*)alloc((size_t)16384 * 4);
  float* bias2 = (float*)alloc(512 * 4);
  float* bias3 = (float*)alloc(384 * 4);
  float* V1 = (float*)alloc(256 * 4);
  float* V2 = (float*)alloc(256 * 4);
  float* Vcat3 = (float*)alloc(256 * 4);
  float* Gpart = (float*)alloc((size_t)313 * 512 * 4);
  float* Gpart2 = (float*)alloc((size_t)8 * 512 * 4);
  float* scsh = (float*)alloc(512 * 4);
  float* ab = (float*)alloc(256 * 4);
  short* Bh1 = (short*)alloc((size_t)256 * 256 * 2);
  short* Bl1 = (short*)alloc((size_t)256 * 256 * 2);
  short* Bh2 = (short*)alloc((size_t)512 * 256 * 2);
  short* Bl2 = (short*)alloc((size_t)512 * 256 * 2);
  short* Bh3 = (short*)alloc((size_t)384 * 256 * 2);
  short* Bl3 = (short*)alloc((size_t)384 * 256 * 2);
  float* Gbuf = (float*)alloc((size_t)NN * 256 * 4);     // G (all three convs)
  float* regB = (float*)alloc((size_t)NN * 256 * 4);     // U1(bf16) -> U3cat(bf16, ld 384)
  float* regC = (float*)alloc((size_t)NN * 256 * 4);     // Xh/Xl (input hi/lo, live to gemm2)
  float* Ucat = (float*)alloc((size_t)NN * 512 * 4);     // U2cat (bf16, ld 512)
  if (off > ws_size) { write_code<<<16, 256, 0, stream>>>(out_mean, 2000.f); return; }

  unsigned short* U1 = (unsigned short*)regB;
  unsigned short* U3 = (unsigned short*)regB;           // U3cat ld 384 (U1 dead after agg1)
  short* Xh = (short*)regC;
  short* Xl = Xh + (size_t)NN * 256;
  float* G = Gbuf;
  unsigned short* U2 = (unsigned short*)Ucat;           // U2cat ld 512

  const int n256 = NN * 256, n128 = NN * 128;
  const int g256 = (n256 + 255) / 256;
  const int nb = (NN + 255) / 256;   // 79 (scan)
  const int nbc = (NN + 63) / 64;    // 313 (colpart)

  // ---- dtype + converts ----
  detect_kernel<<<1, 256, 0, stream>>>((const unsigned short*)d_in[0], flag);
  convert_x_kernel<<<(n256 / 4 + 255) / 256, 256, 0, stream>>>(d_in[0], Xh, Xl, n256 / 4, flag);

  WSpec wsp;
  const int map[28] = {3, 5, 7, 9, 11, 13, 15, 17, 4, 8, 12, 16, 19, 21, 23, 25,
                       20, 22, 24, 26, 27, 28, 29, 30, 31, 33, 32, 34};
  const int offs[28] = {0, 65536, 147456, 212992, 294912, 311296, 335872, 352256,
                        376832, 376896, 376960, 377024, 377088, 442624, 475392, 540928,
                        573696, 573952, 574080, 574336, 574464, 574720, 574976, 575232,
                        575488, 575616, 575744, 575872};
  const int lens[28] = {65536, 81920, 65536, 81920, 16384, 24576, 16384, 24576,
                        64, 64, 64, 64, 65536, 32768, 65536, 32768,
                        256, 128, 256, 128, 256, 256, 256, 256,
                        128, 128, 128, 128};
  for (int i = 0; i < 28; ++i) { wsp.p[i] = d_in[map[i]]; wsp.off[i] = offs[i]; wsp.len[i] = lens[i]; }
  convert_weights<<<dim3(28, 8), 256, 0, stream>>>(wsp, Wf, flag);

  // ---- graph prep ----
  hipMemsetAsync(cnt, 0, NN * 4, stream);
  count_kernel<<<(ET + 255) / 256, 256, 0, stream>>>(ei, cnt);
  scan1_kernel<<<nb, 256, 0, stream>>>(cnt, spart, bsum, dis);
  scan2_kernel<<<1, 128, 0, stream>>>(bsum, nb);
  scan3_kernel<<<nb, 256, 0, stream>>>(spart, bsum, rowptr);
  hipMemsetAsync(cnt, 0, NN * 4, stream);
  hipMemsetAsync(sarr, 0, NN * 4, stream);
  fill_kernel<<<(ET + 255) / 256, 256, 0, stream>>>(ei, d_in[2], dis, rowptr, cnt, csr, sarr, flag);

  // ---- weight prep stage 1 ----
  {
    GJobs jb{};
    auto set = [&](int j, const float* A, const float* B, float* C, int M, int N, int K,
                   int ldc, int bx, int cum) {
      jb.A[j] = A; jb.B[j] = B; jb.C[j] = C; jb.M[j] = M; jb.N[j] = N; jb.K[j] = K;
      jb.ldc[j] = ldc; jb.blkx[j] = bx; jb.cum[j] = cum;
    };
    set(0, Wf + 0,      Wf + 65536,  W1,          256, 256, 256, 256, 4, 16);
    set(1, Wf + 147456, Wf + 212992, WCa,         256, 256, 256, 256, 4, 32);
    set(2, Wf + 294912, Wf + 311296, WCb,         128, 128, 128, 128, 2, 36);
    set(3, Wf + 335872, Wf + 352256, WCc,         128, 128, 128, 128, 2, 40);
    set(4, Wf + 376832, Wf + 131072, V1,          1,   256, 64,  256, 1, 44);
    set(5, Wf + 376896, Wf + 278528, V2,          1,   256, 64,  256, 1, 48);
    set(6, Wf + 376960, Wf + 327680, Vcat3,       1,   128, 64,  128, 1, 50);
    set(7, Wf + 377024, Wf + 368640, Vcat3 + 128, 1,   128, 64,  128, 1, 52);
    jb.njobs = 8;
    gemm64_multi<<<52, 256, 0, stream>>>(jb);
  }
  // ---- weight prep stage 2 ----
  {
    GJobs jb{};
    auto set = [&](int j, const float* A, const float* B, float* C, int M, int N, int K,
                   int ldc, int bx, int cum) {
      jb.A[j] = A; jb.B[j] = B; jb.C[j] = C; jb.M[j] = M; jb.N[j] = N; jb.K[j] = K;
      jb.ldc[j] = ldc; jb.blkx[j] = bx; jb.cum[j] = cum;
    };
    set(0, Wf + 377088, WCa, W2cat,       256, 256, 256, 512, 4, 16);
    set(1, Wf + 573696, WCa, bias2,       1,   256, 256, 512, 1, 20);
    set(2, Wf + 442624, WCb, W3cat,       256, 128, 128, 384, 4, 28);
    set(3, Wf + 442624, WCc, W3cat + 128, 256, 128, 128, 384, 4, 36);
    set(4, Wf + 573952, WCb, bias3,       1,   128, 128, 384, 1, 38);
    set(5, Wf + 573952, WCc, bias3 + 128, 1,   128, 128, 384, 1, 40);
    jb.njobs = 6;
    gemm64_multi<<<40, 256, 0, stream>>>(jb);
  }
  copy_strided<<<256, 256, 0, stream>>>(Wf + 475392, W2cat + 256, 65536, 8, 255, 512);
  copy_strided<<<1, 256, 0, stream>>>(Wf + 574080, bias2 + 256, 256, 8, 255, 512);
  copy_strided<<<128, 256, 0, stream>>>(Wf + 540928, W3cat + 256, 32768, 7, 127, 384);
  copy_strided<<<1, 256, 0, stream>>>(Wf + 574336, bias3 + 256, 128, 7, 127, 384);

  // ---- weight hi/lo k-chunked converts ----
  bconv_kernel<<<256, 256, 0, stream>>>(W1, 256, Bh1, Bl1, 256);
  bconv_kernel<<<512, 256, 0, stream>>>(W2cat, 512, Bh2, Bl2, 512);
  bconv_kernel<<<384, 256, 0, stream>>>(W3cat, 384, Bh3, Bl3, 384);

  // ---- conv1: U1 = X @ W1 ----
  gemm_fused<0><<<625, 512, 0, stream>>>(Xh, Xl, nullptr, nullptr, nullptr, nullptr, nullptr,
                                         Bh1, Bl1, U1, nullptr, NN, 256, 256);
  agg_kernel<<<NN, 64, 0, stream>>>(U1, 256, rowptr, csr, sarr, V1, G);
  colpart_kernel<<<nbc, 256, 0, stream>>>(G, Gpart, 256);
  bnred_kernel<<<dim3(2, 8), 256, 0, stream>>>(Gpart, Gpart2, 512, nbc);
  bnfin_kernel<<<1, 256, 0, stream>>>(Gpart2, Wf + 574464, Wf + 574720, 256, scsh);

  // ---- conv2 + pih ----
  gemm_fused<1><<<625, 512, 0, stream>>>(nullptr, nullptr, G, scsh, Xh, Xl, nullptr,
                                         Bh2, Bl2, U2, bias2, NN, 512, 512);
  agg_kernel<<<NN, 64, 0, stream>>>(U2, 512, rowptr, csr, sarr, V2, G);
  colpart_kernel<<<nbc, 256, 0, stream>>>(G, Gpart, 256);
  bnred_kernel<<<dim3(2, 8), 256, 0, stream>>>(Gpart, Gpart2, 512, nbc);
  bnfin_kernel<<<1, 256, 0, stream>>>(Gpart2, Wf + 574976, Wf + 575232, 256, scsh);

  // ---- conv3 (mean|logstd|pho) ----
  gemm_fused<2><<<625, 512, 0, stream>>>(nullptr, nullptr, G, scsh, nullptr, nullptr, U2,
                                         Bh3, Bl3, U3, bias3, NN, 384, 384);
  agg_kernel<<<NN, 64, 0, stream>>>(U3, 384, rowptr, csr, sarr, Vcat3, G);
  colpart_kernel<<<nbc, 256, 0, stream>>>(G, Gpart, 256);
  bnred_kernel<<<dim3(2, 8), 256, 0, stream>>>(Gpart, Gpart2, 512, nbc);
  bnfin_kernel<<<1, 256, 0, stream>>>(Gpart2, Wf + 575488, Wf + 575744, 256, scsh);
  bnfin2_kernel<<<1, 128, 0, stream>>>(Gpart2, scsh, Wf + 575616, Wf + 575872, ab);
  apply_out_kernel<<<g256, 256, 0, stream>>>(G, scsh, ab, U3, out_mean, out_logstd, n256);
}

// Round 21
// 357.566 us; speedup vs baseline: 1.0723x; 1.0341x over previous
//
#include <hip/hip_runtime.h>

#define NN 20000
#define EE 320000
#define ET (EE + NN)

typedef __attribute__((ext_vector_type(8))) short short8v;
typedef __attribute__((ext_vector_type(4))) float float4v;

__device__ __forceinline__ float b2f(unsigned short u) {
  union { float f; unsigned int i; } c; c.i = ((unsigned int)u) << 16; return c.f;
}
__device__ __forceinline__ unsigned short f2bs(float f) {  // f32 -> bf16 bits, RNE
  union { float f; unsigned int u; } c; c.f = f;
  unsigned int r = c.u + 0x7fffu + ((c.u >> 16) & 1u);
  return (unsigned short)(r >> 16);
}

// ---------------- input dtype detector (flag=1 -> f32, flag=0 -> bf16) ----------------
__global__ void detect_kernel(const unsigned short* __restrict__ x, int* __restrict__ flag) {
  __shared__ int cnt_s;
  if (threadIdx.x == 0) cnt_s = 0;
  __syncthreads();
  int pass = 0;
  for (int j = 0; j < 16; ++j) {
    unsigned short u = x[2 * (threadIdx.x * 16 + j)];
    int e = (u >> 7) & 0xFF;
    if (e >= 96 && e <= 150) pass++;
  }
  atomicAdd(&cnt_s, pass);
  __syncthreads();
  if (threadIdx.x == 0) *flag = (cnt_s < 2458) ? 1 : 0;
}

// x -> hi/lo bf16; also zeroes cnt[] (used later by count_kernel)
__global__ void convert_x_kernel(const void* __restrict__ in,
                                 short* __restrict__ xh, short* __restrict__ xl, int n4,
                                 const int* __restrict__ flag, int* __restrict__ cnt) {
  int i = blockIdx.x * 256 + threadIdx.x;
  if (i < NN) cnt[i] = 0;
  if (i >= n4) return;
  float4 v;
  if (*flag) {
    v = ((const float4*)in)[i];
  } else {
    ushort4 u = ((const ushort4*)in)[i];
    v = make_float4(b2f(u.x), b2f(u.y), b2f(u.z), b2f(u.w));
  }
  ushort4 h, l;
  h.x = f2bs(v.x); l.x = f2bs(v.x - b2f(h.x));
  h.y = f2bs(v.y); l.y = f2bs(v.y - b2f(h.y));
  h.z = f2bs(v.z); l.z = f2bs(v.z - b2f(h.z));
  h.w = f2bs(v.w); l.w = f2bs(v.w - b2f(h.w));
  ((ushort4*)xh)[i] = h;
  ((ushort4*)xl)[i] = l;
}

struct WSpec { const void* p[28]; int off[28]; int len[28]; };
__global__ void convert_weights(WSpec ws, float* __restrict__ out, const int* __restrict__ flag) {
  int b = blockIdx.x;
  int f32m = *flag;
  const void* p = ws.p[b];
  int off = ws.off[b], len4 = ws.len[b] >> 2;
  float4* dst = (float4*)(out + off);
  for (int i = blockIdx.y * 256 + threadIdx.x; i < len4; i += 8 * 256) {
    if (f32m) {
      dst[i] = ((const float4*)p)[i];
    } else {
      ushort4 u = ((const ushort4*)p)[i];
      dst[i] = make_float4(b2f(u.x), b2f(u.y), b2f(u.z), b2f(u.w));
    }
  }
}

// merged bconv: W [K x N] row-major -> k-chunked hi/lo bf16 for all three weight sets
__global__ void bconv_multi(const float* __restrict__ W1, const float* __restrict__ W2,
                            const float* __restrict__ W3,
                            short* __restrict__ Bh1, short* __restrict__ Bl1,
                            short* __restrict__ Bh2, short* __restrict__ Bl2,
                            short* __restrict__ Bh3, short* __restrict__ Bl3) {
  int b = blockIdx.x;
  const float* W; short* Bh; short* Bl; int N; int nb0;
  if (b < 256)      { W = W1; Bh = Bh1; Bl = Bl1; N = 256; nb0 = 0; }
  else if (b < 768) { W = W2; Bh = Bh2; Bl = Bl2; N = 512; nb0 = 256; }
  else              { W = W3; Bh = Bh3; Bl = Bl3; N = 384; nb0 = 768; }
  int idx = (b - nb0) * 256 + threadIdx.x;
  if (idx >= N * 256) return;
  int n = idx >> 8, k = idx & 255;
  float v = W[(size_t)k * N + n];
  unsigned short h = f2bs(v);
  size_t o = ((size_t)(k >> 3) * N + n) * 8 + (k & 7);
  Bh[o] = (short)h;
  Bl[o] = (short)f2bs(v - b2f(h));
}

// ---------------- graph prep: degrees + CSR ----------------
__global__ void count_kernel(const int* __restrict__ ei, int* __restrict__ cnt) {
  int e = blockIdx.x * 256 + threadIdx.x;
  if (e >= ET) return;
  int dst = (e < EE) ? ei[EE + e] : (e - EE);
  atomicAdd(&cnt[dst], 1);
}

// scan1 + dis + sarr-zero fused
__global__ void scan1_kernel(const int* __restrict__ cnt, int* __restrict__ partial,
                             int* __restrict__ bsum, float* __restrict__ dis,
                             float* __restrict__ sarr) {
  __shared__ int sd[256];
  int b = blockIdx.x, t = threadIdx.x;
  int i = b * 256 + t;
  int v = (i < NN) ? cnt[i] : 0;
  if (i < NN) {
    dis[i] = rsqrtf((float)v + 1e-6f);
    sarr[i] = 0.f;
  }
  sd[t] = v;
  __syncthreads();
  for (int off = 1; off < 256; off <<= 1) {
    int x = (t >= off) ? sd[t - off] : 0;
    __syncthreads();
    sd[t] += x;
    __syncthreads();
  }
  if (i < NN) partial[i] = sd[t];
  if (t == 255) bsum[b] = sd[255];
}

__global__ void scan2_kernel(int* __restrict__ bsum, int nb) {
  __shared__ int sd[128];
  int t = threadIdx.x;
  sd[t] = (t < nb) ? bsum[t] : 0;
  __syncthreads();
  for (int off = 1; off < 128; off <<= 1) {
    int x = (t >= off) ? sd[t - off] : 0;
    __syncthreads();
    sd[t] += x;
    __syncthreads();
  }
  if (t < nb) bsum[t] = sd[t];
}

// scan3 + cursor-zero fused (cnt's last reader is scan1)
__global__ void scan3_kernel(const int* __restrict__ partial, const int* __restrict__ bsum,
                             int* __restrict__ rowptr, int* __restrict__ cnt) {
  int i = blockIdx.x * 256 + threadIdx.x;
  if (i == 0) rowptr[0] = 0;
  if (i < NN) {
    int b = i >> 8;
    rowptr[i + 1] = partial[i] + (b ? bsum[b - 1] : 0);
    cnt[i] = 0;   // cursor for fill
  }
}

// packed CSR entry: .x = src, .y = coef bits; edge_attr read raw with dtype flag
__global__ void fill_kernel(const int* __restrict__ ei, const void* __restrict__ ea,
                            const float* __restrict__ dis, const int* __restrict__ rowptr,
                            int* __restrict__ cursor, int2* __restrict__ csr,
                            float* __restrict__ sarr, const int* __restrict__ flag) {
  int e = blockIdx.x * 256 + threadIdx.x;
  if (e >= ET) return;
  int src, dst; float a;
  if (e < EE) {
    src = ei[e]; dst = ei[EE + e];
    a = (*flag) ? ((const float*)ea)[e] : b2f(((const unsigned short*)ea)[e]);
  } else {
    src = dst = e - EE; a = 0.f;
  }
  float coef = dis[src] * dis[dst];
  int pos = rowptr[dst] + atomicAdd(&cursor[dst], 1);
  csr[pos] = make_int2(src, __float_as_int(coef));
  if (a != 0.f) atomicAdd(&sarr[dst], coef * a);
}

// ---------------- batched small GEMMs (64x64 tile, 4x4 micro) ----------------
struct GJobs {
  const float* A[8]; const float* B[8]; float* C[8];
  int M[8], N[8], K[8], ldc[8], blkx[8], cum[8];
  int njobs;
};
__global__ __launch_bounds__(256) void gemm64_multi(GJobs jb) {
  int bid = blockIdx.x;
  int j = 0;
  while (j < jb.njobs - 1 && bid >= jb.cum[j]) ++j;
  int local = bid - (j ? jb.cum[j - 1] : 0);
  const float* A = jb.A[j];
  const float* B = jb.B[j];
  float* C = jb.C[j];
  int M = jb.M[j], N = jb.N[j], K = jb.K[j], ldc = jb.ldc[j];
  int bx = local % jb.blkx[j], by = local / jb.blkx[j];

  __shared__ float As[16][68];
  __shared__ float Bs[16][64];
  int tid = threadIdx.x;
  int row0 = bx * 64, col0 = by * 64;
  int tr = tid >> 4, tc = tid & 15;
  float acc[4][4] = {};
  int lmA = tid >> 2;
  int lkA = (tid & 3) << 2;
  int lkB = tid >> 4;
  int lcB = (tid & 15) << 2;
  for (int k0 = 0; k0 < K; k0 += 16) {
    int gr = row0 + lmA;
    float4 a4 = make_float4(0.f, 0.f, 0.f, 0.f);
    if (gr < M) a4 = *reinterpret_cast<const float4*>(&A[(size_t)gr * K + k0 + lkA]);
    As[lkA + 0][lmA] = a4.x;
    As[lkA + 1][lmA] = a4.y;
    As[lkA + 2][lmA] = a4.z;
    As[lkA + 3][lmA] = a4.w;
    float4 b4 = *reinterpret_cast<const float4*>(&B[(size_t)(k0 + lkB) * N + col0 + lcB]);
    *reinterpret_cast<float4*>(&Bs[lkB][lcB]) = b4;
    __syncthreads();
#pragma unroll
    for (int kk = 0; kk < 16; ++kk) {
      float4 av = *reinterpret_cast<const float4*>(&As[kk][tr << 2]);
      float4 bv = *reinterpret_cast<const float4*>(&Bs[kk][tc << 2]);
      float aa[4] = {av.x, av.y, av.z, av.w};
      float bb[4] = {bv.x, bv.y, bv.z, bv.w};
#pragma unroll
      for (int i = 0; i < 4; ++i)
#pragma unroll
        for (int jj = 0; jj < 4; ++jj) acc[i][jj] += aa[i] * bb[jj];
    }
    __syncthreads();
  }
#pragma unroll
  for (int i = 0; i < 4; ++i) {
    int gr = row0 + (tr << 2) + i;
    if (gr >= M) continue;
#pragma unroll
    for (int jj = 0; jj < 4; ++jj)
      C[(size_t)gr * ldc + col0 + (tc << 2) + jj] = acc[i][jj];
  }
}

// ---------------- merged strided copies ----------------
struct CJobs {
  const float* s[4]; float* d[4];
  int n[4], cshift[4], cmask[4], ldd[4], cum[4];
};
__global__ void copy_multi(CJobs cj) {
  int bid = blockIdx.x;
  int j = 0;
  while (j < 3 && bid >= cj.cum[j]) ++j;
  int local = bid - (j ? cj.cum[j - 1] : 0);
  int idx = local * 256 + threadIdx.x;
  if (idx >= cj.n[j]) return;
  int r = idx >> cj.cshift[j], c = idx & cj.cmask[j];
  cj.d[j][(size_t)r * cj.ldd[j] + c] = cj.s[j][idx];
}

// ---------------- A-resident MFMA GEMM (512 thr, 8 waves) with fused staging ----------------
// MODE 0: A = (Ah,Al) bf16 pair.
// MODE 1: A = split(relu(G*sc+sh) + (Rh+Rl))
// MODE 2: A = split(relu(G*sc+sh) + b2f(ucat[.,256+c]))
#define LOADB(ntv, ktv, BH, BL)                                     \
  {                                                                 \
    int n_ = (ntv) * 128 + w * 16 + lm;                             \
    _Pragma("unroll") for (int ks = 0; ks < 2; ++ks) {              \
      int kc = (ktv) * 8 + ks * 4 + lg;                             \
      size_t o = ((size_t)kc * N + n_) * 8;                         \
      BH[ks] = *reinterpret_cast<const short8v*>(Bh + o);           \
      BL[ks] = *reinterpret_cast<const short8v*>(Bl + o);           \
    }                                                               \
  }

template <int MODE>
__global__ __launch_bounds__(512) void gemm_fused(const short* __restrict__ Ah,
                                                  const short* __restrict__ Al,
                                                  const float* __restrict__ Gsrc,
                                                  const float* __restrict__ scshp,
                                                  const short* __restrict__ Rh,
                                                  const short* __restrict__ Rl,
                                                  const unsigned short* __restrict__ ures,
                                                  const short* __restrict__ Bh,
                                                  const short* __restrict__ Bl,
                                                  unsigned short* __restrict__ C,
                                                  const float* __restrict__ bias,
                                                  int M, int N, int ldc) {
  __shared__ __align__(16) short lds[16384];  // hi [0,8192), lo [8192,16384) shorts
  const int K = 256;
  int tid = threadIdx.x;
  int w = tid >> 6, l = tid & 63;
  int row0 = blockIdx.x * 32;
  int lm = l & 15, lg = l >> 4;

#pragma unroll
  for (int i = 0; i < 2; ++i) {
    int id = i * 512 + tid;
    int r = id >> 5, c = id & 31;
    int gr = row0 + r; if (gr >= M) gr = M - 1;
    int sw = c ^ r;
    if (MODE == 0) {
      *reinterpret_cast<float4*>(lds + r * 256 + sw * 8) =
          *reinterpret_cast<const float4*>(Ah + (size_t)gr * K + c * 8);
      *reinterpret_cast<float4*>(lds + 8192 + r * 256 + sw * 8) =
          *reinterpret_cast<const float4*>(Al + (size_t)gr * K + c * 8);
    } else {
      const float* gp = Gsrc + (size_t)gr * 256 + c * 8;
      float4 g0 = *reinterpret_cast<const float4*>(gp);
      float4 g1 = *reinterpret_cast<const float4*>(gp + 4);
      float4 sc0 = *reinterpret_cast<const float4*>(scshp + c * 8);
      float4 sc1 = *reinterpret_cast<const float4*>(scshp + c * 8 + 4);
      float4 sh0 = *reinterpret_cast<const float4*>(scshp + 256 + c * 8);
      float4 sh1 = *reinterpret_cast<const float4*>(scshp + 256 + c * 8 + 4);
      float vals[8] = {g0.x * sc0.x + sh0.x, g0.y * sc0.y + sh0.y,
                       g0.z * sc0.z + sh0.z, g0.w * sc0.w + sh0.w,
                       g1.x * sc1.x + sh1.x, g1.y * sc1.y + sh1.y,
                       g1.z * sc1.z + sh1.z, g1.w * sc1.w + sh1.w};
      float res[8];
      if (MODE == 1) {
        short8v hv = *reinterpret_cast<const short8v*>(Rh + (size_t)gr * 256 + c * 8);
        short8v lv = *reinterpret_cast<const short8v*>(Rl + (size_t)gr * 256 + c * 8);
#pragma unroll
        for (int j = 0; j < 8; ++j)
          res[j] = b2f((unsigned short)hv[j]) + b2f((unsigned short)lv[j]);
      } else {
        short8v uv = *reinterpret_cast<const short8v*>(
            (const short*)ures + (size_t)gr * 512 + 256 + c * 8);
#pragma unroll
        for (int j = 0; j < 8; ++j) res[j] = b2f((unsigned short)uv[j]);
      }
      short8v hs, ls;
#pragma unroll
      for (int j = 0; j < 8; ++j) {
        float y = fmaxf(vals[j], 0.f) + res[j];
        unsigned short h = f2bs(y);
        hs[j] = (short)h;
        ls[j] = (short)f2bs(y - b2f(h));
      }
      *reinterpret_cast<short8v*>(lds + r * 256 + sw * 8) = hs;
      *reinterpret_cast<short8v*>(lds + 8192 + r * 256 + sw * 8) = ls;
    }
  }
  __syncthreads();

  int NT = N >> 7;
  short8v bhX[2], blX[2], bhY[2], blY[2];
  LOADB(0, 0, bhX, blX);
  for (int nt = 0; nt < NT; ++nt) {
    float4v acc[2] = {};
    int n = nt * 128 + w * 16 + lm;
#pragma unroll
    for (int kt = 0; kt < 4; ++kt) {
      int nt_n = (kt == 3) ? ((nt + 1 < NT) ? nt + 1 : nt) : nt;
      int kt_n = (kt + 1) & 3;
      short8v a_h[2][2], a_l[2][2];
#pragma unroll
      for (int mf = 0; mf < 2; ++mf)
#pragma unroll
        for (int ks = 0; ks < 2; ++ks) {
          int r = mf * 16 + lm;
          int c = kt * 8 + ks * 4 + lg;
          int sw = c ^ r;
          a_h[mf][ks] = *reinterpret_cast<const short8v*>(lds + r * 256 + sw * 8);
          a_l[mf][ks] = *reinterpret_cast<const short8v*>(lds + 8192 + r * 256 + sw * 8);
        }
      if ((kt & 1) == 0) {
        LOADB(nt_n, kt_n, bhY, blY);
#pragma unroll
        for (int mf = 0; mf < 2; ++mf)
#pragma unroll
          for (int ks = 0; ks < 2; ++ks) {
            acc[mf] = __builtin_amdgcn_mfma_f32_16x16x32_bf16(a_h[mf][ks], bhX[ks], acc[mf], 0, 0, 0);
            acc[mf] = __builtin_amdgcn_mfma_f32_16x16x32_bf16(a_h[mf][ks], blX[ks], acc[mf], 0, 0, 0);
            acc[mf] = __builtin_amdgcn_mfma_f32_16x16x32_bf16(a_l[mf][ks], bhX[ks], acc[mf], 0, 0, 0);
          }
      } else {
        LOADB(nt_n, kt_n, bhX, blX);
#pragma unroll
        for (int mf = 0; mf < 2; ++mf)
#pragma unroll
          for (int ks = 0; ks < 2; ++ks) {
            acc[mf] = __builtin_amdgcn_mfma_f32_16x16x32_bf16(a_h[mf][ks], bhY[ks], acc[mf], 0, 0, 0);
            acc[mf] = __builtin_amdgcn_mfma_f32_16x16x32_bf16(a_h[mf][ks], blY[ks], acc[mf], 0, 0, 0);
            acc[mf] = __builtin_amdgcn_mfma_f32_16x16x32_bf16(a_l[mf][ks], bhY[ks], acc[mf], 0, 0, 0);
          }
      }
    }
    float bb = bias ? bias[n] : 0.f;
#pragma unroll
    for (int mf = 0; mf < 2; ++mf)
#pragma unroll
      for (int r = 0; r < 4; ++r) {
        int m = row0 + mf * 16 + lg * 4 + r;
        if (m < M) C[(size_t)m * ldc + n] = f2bs(acc[mf][r] + bb);
      }
  }
}

// ---------------- CSR gather (one node per 64-thread block), int2 CSR, bf16 U ----------------
__global__ void agg_kernel(const unsigned short* __restrict__ U, int ldu,
                           const int* __restrict__ rowptr, const int2* __restrict__ csr,
                           const float* __restrict__ sarr, const float* __restrict__ V,
                           float* __restrict__ G) {
  int i = blockIdx.x, t = threadIdx.x;  // t in [0,64)
  float s = sarr[i];
  float4 v4 = ((const float4*)V)[t];
  float ax = s * v4.x, ay = s * v4.y, az = s * v4.z, aw = s * v4.w;
  int p1 = rowptr[i + 1];
  for (int p = rowptr[i]; p < p1; ++p) {
    int2 e = csr[p];
    float c = __int_as_float(e.y);
    ushort4 u4 = *reinterpret_cast<const ushort4*>(U + (size_t)e.x * ldu + (t << 2));
    ax += c * b2f(u4.x); ay += c * b2f(u4.y); az += c * b2f(u4.z); aw += c * b2f(u4.w);
  }
  *reinterpret_cast<float4*>(G + (size_t)i * 256 + (t << 2)) = make_float4(ax, ay, az, aw);
}

// ---------------- BN stats: 64-row blocks, float4 lanes, LDS cross-team reduce ----------------
__global__ void colpart_kernel(const float* __restrict__ h, float* __restrict__ part, int F) {
  __shared__ float4 sm0[256], sm1[256];
  int t = threadIdx.x;
  int cols4 = F >> 2;
  int lc = t & (cols4 - 1);
  int team = t / cols4;
  int rpi = 256 / cols4;
  int r0 = blockIdx.x * 64;
  int r1 = min(r0 + 64, NN);
  float4 s0 = make_float4(0.f, 0.f, 0.f, 0.f);
  float4 s1 = make_float4(0.f, 0.f, 0.f, 0.f);
  for (int r = r0 + team; r < r1; r += rpi) {
    float4 x = *reinterpret_cast<const float4*>(h + (size_t)r * F + lc * 4);
    s0.x += x.x; s0.y += x.y; s0.z += x.z; s0.w += x.w;
    s1.x += x.x * x.x; s1.y += x.y * x.y; s1.z += x.z * x.z; s1.w += x.w * x.w;
  }
  sm0[t] = s0; sm1[t] = s1;
  __syncthreads();
  if (team == 0) {
    for (int k = 1; k < rpi; ++k) {
      float4 a = sm0[k * cols4 + lc];
      float4 b = sm1[k * cols4 + lc];
      s0.x += a.x; s0.y += a.y; s0.z += a.z; s0.w += a.w;
      s1.x += b.x; s1.y += b.y; s1.z += b.z; s1.w += b.w;
    }
    *reinterpret_cast<float4*>(part + (size_t)blockIdx.x * 2 * F + lc * 4) = s0;
    *reinterpret_cast<float4*>(part + (size_t)blockIdx.x * 2 * F + F + lc * 4) = s1;
  }
}

// parallel partial reduce: part[nb][F2] -> part2[8][F2]
__global__ void bnred_kernel(const float* __restrict__ part, float* __restrict__ part2,
                             int F2, int nb) {
  int c = blockIdx.x * 256 + threadIdx.x;
  if (c >= F2) return;
  int chunk = blockIdx.y;
  int cs = (nb + 7) >> 3;
  int b0 = chunk * cs;
  int b1 = min(b0 + cs, nb);
  float s0 = 0.f, s1 = 0.f, s2 = 0.f, s3 = 0.f;
  int b = b0;
  for (; b + 3 < b1; b += 4) {
    s0 += part[(size_t)(b + 0) * F2 + c];
    s1 += part[(size_t)(b + 1) * F2 + c];
    s2 += part[(size_t)(b + 2) * F2 + c];
    s3 += part[(size_t)(b + 3) * F2 + c];
  }
  for (; b < b1; ++b) s0 += part[(size_t)b * F2 + c];
  part2[(size_t)chunk * F2 + c] = (s0 + s1) + (s2 + s3);
}

__global__ void bnfin_kernel(const float* __restrict__ part2, const float* __restrict__ gamma,
                             const float* __restrict__ beta, int F,
                             float* __restrict__ scsh) {
  int t = threadIdx.x;
  int F2 = 2 * F;
  float s0 = 0.f, s1 = 0.f;
#pragma unroll
  for (int b = 0; b < 8; ++b) {
    s0 += part2[(size_t)b * F2 + t];
    s1 += part2[(size_t)b * F2 + F + t];
  }
  const float invn = 1.f / (float)NN;
  float m = s0 * invn;
  float var = s1 * invn - m * m;
  float sc = gamma[t] * rsqrtf(var + 1e-5f);
  scsh[t] = sc;
  scsh[F + t] = beta[t] - m * sc;
}

// analytic BN-of-BN for logstd cols (128..255 of G)
__global__ void bnfin2_kernel(const float* __restrict__ part2, const float* __restrict__ scsh,
                              const float* __restrict__ gamma2, const float* __restrict__ beta2,
                              float* __restrict__ ab) {
  int t = threadIdx.x;  // 0..127
  int c = 128 + t;
  float s0 = 0.f, s1 = 0.f;
#pragma unroll
  for (int b = 0; b < 8; ++b) {
    s0 += part2[(size_t)b * 512 + c];
    s1 += part2[(size_t)b * 512 + 256 + c];
  }
  const float invn = 1.f / (float)NN;
  float m_g = s0 * invn;
  float v_g = s1 * invn - m_g * m_g;
  float sc1 = scsh[c];
  float sh1 = scsh[256 + c];
  float m_L = m_g * sc1 + sh1;
  float v_L = v_g * sc1 * sc1;
  float sc2 = gamma2[t] * rsqrtf(v_L + 1e-5f);
  float sh2 = beta2[t] - m_L * sc2;
  ab[t] = sc1 * (1.f + sc2);
  ab[128 + t] = sh1 * (1.f + sc2) + sh2;
}

// ---------------- merged output epilogue ----------------
__global__ void apply_out_kernel(const float* __restrict__ g, const float* __restrict__ scsh,
                                 const float* __restrict__ ab,
                                 const unsigned short* __restrict__ ucat,
                                 float* __restrict__ out_mean, float* __restrict__ out_logstd,
                                 int n) {
  int idx = blockIdx.x * 256 + threadIdx.x;
  if (idx >= n) return;
  int r = idx >> 8, c = idx & 255;
  float v = g[idx];
  if (c < 128) {
    out_mean[(size_t)r * 128 + c] = v * scsh[c] + scsh[256 + c] + b2f(ucat[(size_t)r * 384 + 256 + c]);
  } else {
    int cc = c - 128;
    out_logstd[(size_t)r * 128 + cc] = v * ab[cc] + ab[128 + cc];
  }
}

// ---------------- host-side failure codes ----------------
__global__ void write_code(float* __restrict__ out, float code) {
  int i = blockIdx.x * 256 + threadIdx.x;
  if (i < 4096) out[i] = code;
}

// ---------------- launch ----------------
extern "C" void kernel_launch(void* const* d_in, const int* in_sizes, int n_in,
                              void* d_out, int out_size, void* d_ws, size_t ws_size,
                              hipStream_t stream) {
  float* out_mean = (float*)d_out;
  float* out_logstd = out_mean + (size_t)NN * 128;

  static const int expect[35] = {5120000, 640000, 320000,
                                 65536, 64, 81920, 256,  65536, 64, 81920, 256,
                                 16384, 64, 24576, 128,  16384, 64, 24576, 128,
                                 65536, 256, 32768, 128, 65536, 256, 32768, 128,
                                 256, 256, 256, 256, 128, 128, 128, 128};
  if (n_in != 35) { write_code<<<16, 256, 0, stream>>>(out_mean, 900.f); return; }
  if (out_size != 5120000) { write_code<<<16, 256, 0, stream>>>(out_mean, 950.f); return; }
  for (int i = 0; i < 35; ++i)
    if (in_sizes[i] != expect[i]) {
      write_code<<<16, 256, 0, stream>>>(out_mean, 1000.f + 10.f * i);
      return;
    }

  const int* ei = (const int*)d_in[1];

  char* w = (char*)d_ws;
  size_t off = 0;
  auto alloc = [&](size_t bytes) -> void* {
    void* p = w + off;
    off += (bytes + 255) & ~(size_t)255;
    return p;
  };
  int* flag = (int*)alloc(4);
  int* cnt = (int*)alloc(NN * 4);
  int* rowptr = (int*)alloc((NN + 1) * 4);
  int* bsum = (int*)alloc(128 * 4);
  int* spart = (int*)alloc(NN * 4);
  int2* csr = (int2*)alloc((size_t)ET * 8);
  float* dis = (float*)alloc(NN * 4);
  float* sarr = (float*)alloc(NN * 4);
  float* Wf = (float*)alloc((size_t)576000 * 4);
  float* W1 = (float*)alloc((size_t)65536 * 4);
  float* W2cat = (float*)alloc((size_t)131072 * 4);
  float* W3cat = (float*)alloc((size_t)98304 * 4);
  float* WCa = (float*)alloc((size_t)65536 * 4);
  float* WCb = (float*)alloc((size_t)16384 * 4);
  float* WCc = (float*)alloc((size_t)16384 * 4);
  float* bias2 = (float*)alloc(512 * 4);
  float* bias3 = (float*)alloc(384 * 4);
  float* V1 = (float*)alloc(256 * 4);
  float* V2 = (float*)alloc(256 * 4);
  float* Vcat3 = (float*)alloc(256 * 4);
  float* Gpart = (float*)alloc((size_t)313 * 512 * 4);
  float* Gpart2 = (float*)alloc((size_t)8 * 512 * 4);
  float* scsh = (float*)alloc(512 * 4);
  float* ab = (float*)alloc(256 * 4);
  short* Bh1 = (short*)alloc((size_t)256 * 256 * 2);
  short* Bl1 = (short*)alloc((size_t)256 * 256 * 2);
  short* Bh2 = (short*)alloc((size_t)512 * 256 * 2);
  short* Bl2 = (short*)alloc((size_t)512 * 256 * 2);
  short* Bh3 = (short*)alloc((size_t)384 * 256 * 2);
  short* Bl3 = (short*)alloc((size_t)384 * 256 * 2);
  float* Gbuf = (float*)alloc((size_t)NN * 256 * 4);     // G (all three convs)
  float* regB = (float*)alloc((size_t)NN * 256 * 4);     // U1(bf16) -> U3cat(bf16, ld 384)
  float* regC = (float*)alloc((size_t)NN * 256 * 4);     // Xh/Xl (input hi/lo, live to gemm2)
  float* Ucat = (float*)alloc((size_t)NN * 512 * 4);     // U2cat (bf16, ld 512)
  if (off > ws_size) { write_code<<<16, 256, 0, stream>>>(out_mean, 2000.f); return; }

  unsigned short* U1 = (unsigned short*)regB;
  unsigned short* U3 = (unsigned short*)regB;           // U3cat ld 384 (U1 dead after agg1)
  short* Xh = (short*)regC;
  short* Xl = Xh + (size_t)NN * 256;
  float* G = Gbuf;
  unsigned short* U2 = (unsigned short*)Ucat;           // U2cat ld 512

  const int n256 = NN * 256;
  const int g256 = (n256 + 255) / 256;
  const int nb = (NN + 255) / 256;   // 79 (scan)
  const int nbc = (NN + 63) / 64;    // 313 (colpart)

  // ---- dtype + converts (convert_x also zeroes cnt) ----
  detect_kernel<<<1, 256, 0, stream>>>((const unsigned short*)d_in[0], flag);
  convert_x_kernel<<<(n256 / 4 + 255) / 256, 256, 0, stream>>>(d_in[0], Xh, Xl, n256 / 4, flag, cnt);

  WSpec wsp;
  const int map[28] = {3, 5, 7, 9, 11, 13, 15, 17, 4, 8, 12, 16, 19, 21, 23, 25,
                       20, 22, 24, 26, 27, 28, 29, 30, 31, 33, 32, 34};
  const int offs[28] = {0, 65536, 147456, 212992, 294912, 311296, 335872, 352256,
                        376832, 376896, 376960, 377024, 377088, 442624, 475392, 540928,
                        573696, 573952, 574080, 574336, 574464, 574720, 574976, 575232,
                        575488, 575616, 575744, 575872};
  const int lens[28] = {65536, 81920, 65536, 81920, 16384, 24576, 16384, 24576,
                        64, 64, 64, 64, 65536, 32768, 65536, 32768,
                        256, 128, 256, 128, 256, 256, 256, 256,
                        128, 128, 128, 128};
  for (int i = 0; i < 28; ++i) { wsp.p[i] = d_in[map[i]]; wsp.off[i] = offs[i]; wsp.len[i] = lens[i]; }
  convert_weights<<<dim3(28, 8), 256, 0, stream>>>(wsp, Wf, flag);

  // ---- graph prep (memsets folded into scan kernels) ----
  count_kernel<<<(ET + 255) / 256, 256, 0, stream>>>(ei, cnt);
  scan1_kernel<<<nb, 256, 0, stream>>>(cnt, spart, bsum, dis, sarr);
  scan2_kernel<<<1, 128, 0, stream>>>(bsum, nb);
  scan3_kernel<<<nb, 256, 0, stream>>>(spart, bsum, rowptr, cnt);
  fill_kernel<<<(ET + 255) / 256, 256, 0, stream>>>(ei, d_in[2], dis, rowptr, cnt, csr, sarr, flag);

  // ---- weight prep stage 1 ----
  {
    GJobs jb{};
    auto set = [&](int j, const float* A, const float* B, float* C, int M, int N, int K,
                   int ldc, int bx, int cum) {
      jb.A[j] = A; jb.B[j] = B; jb.C[j] = C; jb.M[j] = M; jb.N[j] = N; jb.K[j] = K;
      jb.ldc[j] = ldc; jb.blkx[j] = bx; jb.cum[j] = cum;
    };
    set(0, Wf + 0,      Wf + 65536,  W1,          256, 256, 256, 256, 4, 16);
    set(1, Wf + 147456, Wf + 212992, WCa,         256, 256, 256, 256, 4, 32);
    set(2, Wf + 294912, Wf + 311296, WCb,         128, 128, 128, 128, 2, 36);
    set(3, Wf + 335872, Wf + 352256, WCc,         128, 128, 128, 128, 2, 40);
    set(4, Wf + 376832, Wf + 131072, V1,          1,   256, 64,  256, 1, 44);
    set(5, Wf + 376896, Wf + 278528, V2,          1,   256, 64,  256, 1, 48);
    set(6, Wf + 376960, Wf + 327680, Vcat3,       1,   128, 64,  128, 1, 50);
    set(7, Wf + 377024, Wf + 368640, Vcat3 + 128, 1,   128, 64,  128, 1, 52);
    jb.njobs = 8;
    gemm64_multi<<<52, 256, 0, stream>>>(jb);
  }
  // ---- weight prep stage 2 ----
  {
    GJobs jb{};
    auto set = [&](int j, const float* A, const float* B, float* C, int M, int N, int K,
                   int ldc, int bx, int cum) {
      jb.A[j] = A; jb.B[j] = B; jb.C[j] = C; jb.M[j] = M; jb.N[j] = N; jb.K[j] = K;
      jb.ldc[j] = ldc; jb.blkx[j] = bx; jb.cum[j] = cum;
    };
    set(0, Wf + 377088, WCa, W2cat,       256, 256, 256, 512, 4, 16);
    set(1, Wf + 573696, WCa, bias2,       1,   256, 256, 512, 1, 20);
    set(2, Wf + 442624, WCb, W3cat,       256, 128, 128, 384, 4, 28);
    set(3, Wf + 442624, WCc, W3cat + 128, 256, 128, 128, 384, 4, 36);
    set(4, Wf + 573952, WCb, bias3,       1,   128, 128, 384, 1, 38);
    set(5, Wf + 573952, WCc, bias3 + 128, 1,   128, 128, 384, 1, 40);
    jb.njobs = 6;
    gemm64_multi<<<40, 256, 0, stream>>>(jb);
  }
  {
    CJobs cj{};
    cj.s[0] = Wf + 475392; cj.d[0] = W2cat + 256; cj.n[0] = 65536; cj.cshift[0] = 8; cj.cmask[0] = 255; cj.ldd[0] = 512; cj.cum[0] = 256;
    cj.s[1] = Wf + 574080; cj.d[1] = bias2 + 256; cj.n[1] = 256;   cj.cshift[1] = 8; cj.cmask[1] = 255; cj.ldd[1] = 512; cj.cum[1] = 257;
    cj.s[2] = Wf + 540928; cj.d[2] = W3cat + 256; cj.n[2] = 32768; cj.cshift[2] = 7; cj.cmask[2] = 127; cj.ldd[2] = 384; cj.cum[2] = 385;
    cj.s[3] = Wf + 574336; cj.d[3] = bias3 + 256; cj.n[3] = 128;   cj.cshift[3] = 7; cj.cmask[3] = 127; cj.ldd[3] = 384; cj.cum[3] = 386;
    copy_multi<<<386, 256, 0, stream>>>(cj);
  }

  // ---- weight hi/lo k-chunked converts (merged) ----
  bconv_multi<<<1152, 256, 0, stream>>>(W1, W2cat, W3cat, Bh1, Bl1, Bh2, Bl2, Bh3, Bl3);

  // ---- conv1: U1 = X @ W1 ----
  gemm_fused<0><<<625, 512, 0, stream>>>(Xh, Xl, nullptr, nullptr, nullptr, nullptr, nullptr,
                                         Bh1, Bl1, U1, nullptr, NN, 256, 256);
  agg_kernel<<<NN, 64, 0, stream>>>(U1, 256, rowptr, csr, sarr, V1, G);
  colpart_kernel<<<nbc, 256, 0, stream>>>(G, Gpart, 256);
  bnred_kernel<<<dim3(2, 8), 256, 0, stream>>>(Gpart, Gpart2, 512, nbc);
  bnfin_kernel<<<1, 256, 0, stream>>>(Gpart2, Wf + 574464, Wf + 574720, 256, scsh);

  // ---- conv2 + pih ----
  gemm_fused<1><<<625, 512, 0, stream>>>(nullptr, nullptr, G, scsh, Xh, Xl, nullptr,
                                         Bh2, Bl2, U2, bias2, NN, 512, 512);
  agg_kernel<<<NN, 64, 0, stream>>>(U2, 512, rowptr, csr, sarr, V2, G);
  colpart_kernel<<<nbc, 256, 0, stream>>>(G, Gpart, 256);
  bnred_kernel<<<dim3(2, 8), 256, 0, stream>>>(Gpart, Gpart2, 512, nbc);
  bnfin_kernel<<<1, 256, 0, stream>>>(Gpart2, Wf + 574976, Wf + 575232, 256, scsh);

  // ---- conv3 (mean|logstd|pho) ----
  gemm_fused<2><<<625, 512, 0, stream>>>(nullptr, nullptr, G, scsh, nullptr, nullptr, U2,
                                         Bh3, Bl3, U3, bias3, NN, 384, 384);
  agg_kernel<<<NN, 64, 0, stream>>>(U3, 384, rowptr, csr, sarr, Vcat3, G);
  colpart_kernel<<<nbc, 256, 0, stream>>>(G, Gpart, 256);
  bnred_kernel<<<dim3(2, 8), 256, 0, stream>>>(Gpart, Gpart2, 512, nbc);
  bnfin_kernel<<<1, 256, 0, stream>>>(Gpart2, Wf + 575488, Wf + 575744, 256, scsh);
  bnfin2_kernel<<<1, 128, 0, stream>>>(Gpart2, scsh, Wf + 575616, Wf + 575872, ab);
  apply_out_kernel<<<g256, 256, 0, stream>>>(G, scsh, ab, U3, out_mean, out_logstd, n256);
}